// Round 7
// baseline (708.791 us; speedup 1.0000x reference)
//
#include <hip/hip_runtime.h>
#include <math.h>

// ---------------------------------------------------------------------------
// MemoryAugmentedNetwork — R6b: 6 dispatches, BK=64 GEMM core, attn2 merged
// into attn1 launch, final GEMM rides the big output write.
// (R6 with the nontemporal-store type fixed: ext_vector f32x4, not HIP float4.)
// Shapes: B=2048, IN=1024, E=512, M=256, NB=H=8, D=64
// Algebra (exact): shared K/V; mean->out_w commute; MHA2 collapse;
// W1=wq@blk_w; Wuv=wv@out_w (uvb = cb@Wuv^T + wv@out_b);
// final = [ctx2core | uvb] @ [W2 | W2]^T + bias2,  W2=dec_w@out_w,
// bias2 = dec_b + dec_w@out_b.
// Numerics: split-bf16 (a=ah+al), C=AhBh+AhBl+AlBh, f32 accum.
// ---------------------------------------------------------------------------

typedef __attribute__((ext_vector_type(8))) short short8;
typedef __attribute__((ext_vector_type(4))) float f32x4;
typedef unsigned short u16;

__device__ inline u16 bf16_rn(float x) {
    unsigned u = __float_as_uint(x);
    unsigned r = (u + 0x7FFFu + ((u >> 16) & 1u)) >> 16;
    return (u16)r;
}
__device__ inline float bf16_f(u16 h) { return __uint_as_float(((unsigned)h) << 16); }

// ======================= prep: split + transpose + bias ====================
__global__ __launch_bounds__(256)
void prep_all(const float* __restrict__ x, const float* __restrict__ mm,
              const float* __restrict__ ew, const float* __restrict__ iw,
              const float* __restrict__ ow, const float* __restrict__ dw,
              const float* __restrict__ blk_w,
              const float* __restrict__ in_b, const float* __restrict__ blk_b,
              const float* __restrict__ out_b, const float* __restrict__ dec_b,
              u16* __restrict__ xh, u16* __restrict__ xl,
              u16* __restrict__ mh, u16* __restrict__ ml,
              u16* __restrict__ ewh, u16* __restrict__ ewl,
              u16* __restrict__ iwh, u16* __restrict__ iwl,
              u16* __restrict__ owh, u16* __restrict__ owl,
              u16* __restrict__ dwh, u16* __restrict__ dwl,
              u16* __restrict__ bwTh, u16* __restrict__ bwTl,
              u16* __restrict__ owTh, u16* __restrict__ owTl,
              float* __restrict__ bias1, float* __restrict__ bias2,
              float* __restrict__ bias_uv)
{
    __shared__ float T[32][33];
    const int id = blockIdx.x;
    const int t = threadIdx.x;
    if (id < 2304) {
        const int z = id >> 8, within = id & 255;
        const float* s; u16 *dh, *dl;
        if (z < 8) { s = blk_w + (long long)z * 262144;
                     dh = bwTh + (long long)z * 262144; dl = bwTl + (long long)z * 262144; }
        else       { s = ow; dh = owTh; dl = owTl; }
        const int c0 = (within & 15) * 32, r0 = (within >> 4) * 32;
        const int tx = t & 31, ty = t >> 5;
        #pragma unroll
        for (int rr = 0; rr < 4; ++rr)
            T[ty + rr * 8][tx] = s[(long long)(r0 + ty + rr * 8) * 512 + c0 + tx];
        __syncthreads();
        #pragma unroll
        for (int rr = 0; rr < 4; ++rr) {
            float v = T[tx][ty + rr * 8];
            long long o = (long long)(c0 + ty + rr * 8) * 512 + r0 + tx;
            u16 hh = bf16_rn(v);
            dh[o] = hh; dl[o] = bf16_rn(v - bf16_f(hh));
        }
    } else if (id < 2326) {
        int idx = (id - 2304) * 256 + t;   // 5632
        if (idx < 4096) {
            int n = idx >> 9, f = idx & 511;
            const float* wr_ = iw + (long long)f * 512;
            const float* bb  = blk_b + n * 512;
            float s = in_b[f];
            for (int o = 0; o < 512; ++o) s += wr_[o] * bb[o];
            bias1[idx] = s;
        } else if (idx < 5120) {
            int i = idx - 4096;
            const float* dr = dw + (long long)i * 512;
            float s = dec_b[i];
            for (int f = 0; f < 512; ++f) s += dr[f] * out_b[f];
            bias2[i] = s;
        } else if (idx < 5632) {
            int f = idx - 5120;
            const float* wv = iw + (long long)(1024 + f) * 512;
            float s = 0.f;
            for (int e = 0; e < 512; ++e) s += wv[e] * out_b[e];
            bias_uv[f] = s;
        }
    } else {
        const long long total = 1081344;
        const long long stride = 2048LL * 256;
        for (long long i = (long long)(id - 2326) * 256 + t; i < total; i += stride) {
            const float* src; u16 *hi, *lo; long long j;
            if (i < 524288)      { src = x;  hi = xh;  lo = xl;  j = i; }
            else if (i < 557056) { src = mm; hi = mh;  lo = ml;  j = i - 524288; }
            else if (i < 688128) { src = ew; hi = ewh; lo = ewl; j = i - 557056; }
            else if (i < 884736) { src = iw; hi = iwh; lo = iwl; j = i - 688128; }
            else if (i < 950272) { src = ow; hi = owh; lo = owl; j = i - 884736; }
            else                 { src = dw; hi = dwh; lo = dwl; j = i - 950272; }
            float4 v = reinterpret_cast<const float4*>(src)[j];
            u16 h0 = bf16_rn(v.x), h1 = bf16_rn(v.y), h2 = bf16_rn(v.z), h3 = bf16_rn(v.w);
            ushort4 hv = {h0, h1, h2, h3};
            ushort4 lv = {bf16_rn(v.x - bf16_f(h0)), bf16_rn(v.y - bf16_f(h1)),
                          bf16_rn(v.z - bf16_f(h2)), bf16_rn(v.w - bf16_f(h3))};
            reinterpret_cast<ushort4*>(hi)[j] = hv;
            reinterpret_cast<ushort4*>(lo)[j] = lv;
        }
    }
}

// ===================== generalized descriptor GEMM core (BK=64) ============
// C = act( (A @ B^T + bias) * scale ); omode 0=f32, 1=planes,
// 2=planes transposed (C[col*ldc+row]).  BM=128 BN=64 BK=64, 4 waves.
struct ZD {
    const u16 *Ah, *Al, *Bh, *Bl;
    const float* bias;
    float* Cf; u16 *Ch, *Cl;
    int M, lda, ldb, ldc, K, act, omode;
    float scale;
};
template<int NZ> struct ZPack { ZD d[NZ]; };

__device__ __forceinline__ void gemm_zd(const ZD& dz, int m0, int n0,
    u16 (*Ash)[72], u16 (*Asl)[72], u16 (*Bsh)[72], u16 (*Bsl)[72])
{
    const int t  = threadIdx.x;
    const int r8 = t >> 3;            // 0..31
    const int ck = (t & 7) << 3;      // k-offset 0..56
    const int lane = t & 63;
    const int wid  = t >> 6;
    const int wr = (wid >> 1) * 64;
    const int wc = (wid & 1) * 32;
    const int lr = lane & 15;
    const int g  = lane >> 4;         // 0..3

    f32x4 acc[4][2];
    const f32x4 zero = {0.f, 0.f, 0.f, 0.f};
    #pragma unroll
    for (int i = 0; i < 4; ++i)
        #pragma unroll
        for (int j = 0; j < 2; ++j) acc[i][j] = zero;

    for (int k0 = 0; k0 < dz.K; k0 += 64) {
        int4 vah[4], val[4], vbh[2], vbl[2];
        #pragma unroll
        for (int p2 = 0; p2 < 4; ++p2) {
            long long row = (long long)(m0 + r8 + 32 * p2) * dz.lda + k0 + ck;
            vah[p2] = *reinterpret_cast<const int4*>(dz.Ah + row);
            val[p2] = *reinterpret_cast<const int4*>(dz.Al + row);
        }
        #pragma unroll
        for (int p2 = 0; p2 < 2; ++p2) {
            long long row = (long long)(n0 + r8 + 32 * p2) * dz.ldb + k0 + ck;
            vbh[p2] = *reinterpret_cast<const int4*>(dz.Bh + row);
            vbl[p2] = *reinterpret_cast<const int4*>(dz.Bl + row);
        }
        __syncthreads();
        #pragma unroll
        for (int p2 = 0; p2 < 4; ++p2) {
            *reinterpret_cast<int4*>(&Ash[r8 + 32 * p2][ck]) = vah[p2];
            *reinterpret_cast<int4*>(&Asl[r8 + 32 * p2][ck]) = val[p2];
        }
        #pragma unroll
        for (int p2 = 0; p2 < 2; ++p2) {
            *reinterpret_cast<int4*>(&Bsh[r8 + 32 * p2][ck]) = vbh[p2];
            *reinterpret_cast<int4*>(&Bsl[r8 + 32 * p2][ck]) = vbl[p2];
        }
        __syncthreads();

        #pragma unroll
        for (int kk = 0; kk < 2; ++kk) {
            const int lk = kk * 32 + g * 8;
            short8 fah[4], fal[4], fbh[2], fbl[2];
            #pragma unroll
            for (int i = 0; i < 4; ++i) {
                fah[i] = *reinterpret_cast<const short8*>(&Ash[wr + i * 16 + lr][lk]);
                fal[i] = *reinterpret_cast<const short8*>(&Asl[wr + i * 16 + lr][lk]);
            }
            #pragma unroll
            for (int j = 0; j < 2; ++j) {
                fbh[j] = *reinterpret_cast<const short8*>(&Bsh[wc + j * 16 + lr][lk]);
                fbl[j] = *reinterpret_cast<const short8*>(&Bsl[wc + j * 16 + lr][lk]);
            }
            #pragma unroll
            for (int i = 0; i < 4; ++i)
                #pragma unroll
                for (int j = 0; j < 2; ++j) {
                    acc[i][j] = __builtin_amdgcn_mfma_f32_16x16x32_bf16(fah[i], fbh[j], acc[i][j], 0, 0, 0);
                    acc[i][j] = __builtin_amdgcn_mfma_f32_16x16x32_bf16(fah[i], fbl[j], acc[i][j], 0, 0, 0);
                    acc[i][j] = __builtin_amdgcn_mfma_f32_16x16x32_bf16(fal[i], fbh[j], acc[i][j], 0, 0, 0);
                }
        }
    }

    #pragma unroll
    for (int j = 0; j < 2; ++j) {
        const int col = n0 + wc + j * 16 + lr;
        const float bv = dz.bias ? dz.bias[col] : 0.f;
        #pragma unroll
        for (int i = 0; i < 4; ++i) {
            #pragma unroll
            for (int q = 0; q < 4; ++q) {
                const int row = m0 + wr + i * 16 + ((lane >> 4) << 2) + q;
                float v = (acc[i][j][q] + bv) * dz.scale;
                if (dz.act) v = tanhf(v);
                if (dz.omode == 0) {
                    dz.Cf[(long long)row * dz.ldc + col] = v;
                } else {
                    long long off = (dz.omode == 1)
                        ? (long long)row * dz.ldc + col
                        : (long long)col * dz.ldc + row;
                    u16 h = bf16_rn(v);
                    dz.Ch[off] = h;
                    dz.Cl[off] = bf16_rn(v - bf16_f(h));
                }
            }
        }
    }
}

template<int NZ>
__global__ __launch_bounds__(256)
void gemm_multi(ZPack<NZ> pk)
{
    __shared__ u16 Ash[128][72];
    __shared__ u16 Asl[128][72];
    __shared__ u16 Bsh[64][72];
    __shared__ u16 Bsl[64][72];
    const ZD dz = pk.d[blockIdx.z];
    const int m0 = blockIdx.x * 128;
    if (m0 >= dz.M) return;
    gemm_zd(dz, m0, blockIdx.y * 64, Ash, Asl, Bsh, Bsl);
}

// ======================= fused attention (device body) =====================
// 128 q-rows x 256 keys x 64 d; K in 2 halves; PV in 4 key-quarters; 72KB LDS.
// MODE 0: Q = qp1 slice, rows=q*16+bb; epilogue q-mean -> cb (ldc 512).
// MODE 1: Q = qp2; epilogue -> acat (ldc 1024, cols 0..511), NO uv term.
template<int MODE>
__device__ __forceinline__ void attn_body(char* smem, int bxblk, int h,
    const u16* __restrict__ Qph, const u16* __restrict__ Qpl,
    const u16* __restrict__ Kvh, const u16* __restrict__ Kvl,
    const u16* __restrict__ VTh, const u16* __restrict__ VTl,
    u16* __restrict__ Oh, u16* __restrict__ Ol)
{
    const int t = threadIdx.x;
    const int lane = t & 63, w = t >> 6;
    const int l15 = lane & 15, g = lane >> 4;
    const int wr = w * 32;
    const int b0 = bxblk * (MODE == 0 ? 16 : 128);

    u16* Qs = (u16*)smem;            // [2][128][72] = 36864 B
    char* KsB = smem + 36864;        // [2][128][72] u16 = 36864 B

    for (int c = t; c < 2048; c += 256) {
        int plane = c >> 10, rem = c & 1023;
        int row = rem >> 3, seg = rem & 7;
        const u16* src = plane ? Qpl : Qph;
        long long addr;
        if (MODE == 0) {
            int q = row >> 4, bb = row & 15;
            addr = ((long long)q * 2048 + b0 + bb) * 512 + h * 64 + seg * 8;
        } else {
            addr = (long long)(b0 + row) * 512 + h * 64 + seg * 8;
        }
        *(int4*)(&Qs[plane * 9216 + row * 72 + seg * 8]) = *(const int4*)(src + addr);
    }

    f32x4 sacc[2][16];
    const f32x4 zero = {0.f, 0.f, 0.f, 0.f};
    #pragma unroll
    for (int i = 0; i < 2; ++i)
        #pragma unroll
        for (int j = 0; j < 16; ++j) sacc[i][j] = zero;

    short8 qfh[2][2], qfl[2][2];

    for (int kh = 0; kh < 2; ++kh) {
        if (kh) __syncthreads();
        for (int c = t; c < 2048; c += 256) {
            int plane = c >> 10, rem = c & 1023;
            int key = rem >> 3, seg = rem & 7;
            const u16* src = plane ? Kvl : Kvh;
            *(int4*)(KsB + plane * 18432 + key * 144 + seg * 16) =
                *(const int4*)(src + (long long)(kh * 128 + key) * 1024 + h * 64 + seg * 8);
        }
        __syncthreads();
        if (kh == 0) {
            #pragma unroll
            for (int i = 0; i < 2; ++i)
                #pragma unroll
                for (int kf = 0; kf < 2; ++kf) {
                    int ro = (wr + 16 * i + l15) * 72 + kf * 32 + g * 8;
                    qfh[i][kf] = *(const short8*)(&Qs[ro]);
                    qfl[i][kf] = *(const short8*)(&Qs[9216 + ro]);
                }
        }
        #pragma unroll
        for (int j = 0; j < 8; ++j) {
            int jg = kh * 8 + j;
            #pragma unroll
            for (int kf = 0; kf < 2; ++kf) {
                const char* kb = KsB + (j * 16 + l15) * 144 + (kf * 32 + g * 8) * 2;
                short8 kbh = *(const short8*)(kb);
                short8 kbl = *(const short8*)(kb + 18432);
                #pragma unroll
                for (int i = 0; i < 2; ++i) {
                    sacc[i][jg] = __builtin_amdgcn_mfma_f32_16x16x32_bf16(qfh[i][kf], kbh, sacc[i][jg], 0, 0, 0);
                    sacc[i][jg] = __builtin_amdgcn_mfma_f32_16x16x32_bf16(qfh[i][kf], kbl, sacc[i][jg], 0, 0, 0);
                    sacc[i][jg] = __builtin_amdgcn_mfma_f32_16x16x32_bf16(qfl[i][kf], kbh, sacc[i][jg], 0, 0, 0);
                }
            }
        }
    }

    float inv[2][4];
    #pragma unroll
    for (int i = 0; i < 2; ++i)
        #pragma unroll
        for (int q = 0; q < 4; ++q) {
            float m = -1e30f;
            #pragma unroll
            for (int j = 0; j < 16; ++j) m = fmaxf(m, sacc[i][j][q]);
            #pragma unroll
            for (int off = 1; off <= 8; off <<= 1) m = fmaxf(m, __shfl_xor(m, off, 64));
            #pragma unroll
            for (int j = 0; j < 16; ++j) sacc[i][j][q] = __expf(sacc[i][j][q] - m);
            float s = 0.f;
            #pragma unroll
            for (int j = 0; j < 16; ++j) s += sacc[i][j][q];
            #pragma unroll
            for (int off = 1; off <= 8; off <<= 1) s += __shfl_xor(s, off, 64);
            inv[i][q] = 1.0f / s;
        }

    f32x4 ctx[2][4];
    #pragma unroll
    for (int i = 0; i < 2; ++i)
        #pragma unroll
        for (int jd = 0; jd < 4; ++jd) ctx[i][jd] = zero;

    for (int qt = 0; qt < 4; ++qt) {
        __syncthreads();
        #pragma unroll
        for (int i = 0; i < 2; ++i)
            #pragma unroll
            for (int jj = 0; jj < 4; ++jj) {
                int jg = qt * 4 + jj;
                #pragma unroll
                for (int q = 0; q < 4; ++q) {
                    int row = wr + 16 * i + 4 * g + q;
                    int key = jj * 16 + l15;
                    float pv = sacc[i][jg][q];
                    u16 ph = bf16_rn(pv);
                    u16 pl = bf16_rn(pv - bf16_f(ph));
                    int byt = row * 128 + ((key * 2) ^ ((row & 7) << 4));
                    *(u16*)(smem + byt) = ph;
                    *(u16*)(smem + 16384 + byt) = pl;
                }
            }
        for (int c = t; c < 1024; c += 256) {
            int plane = c >> 9, rem = c & 511;
            int d = rem >> 3, seg = rem & 7;
            const u16* src = plane ? VTl : VTh;
            int4 v = *(const int4*)(src + (long long)h * 16384 + d * 256 + qt * 64 + seg * 8);
            int byt = 36864 + plane * 8192 + d * 128 + ((seg * 16) ^ ((d & 7) << 4));
            *(int4*)(smem + byt) = v;
        }
        __syncthreads();

        short8 pah[2][2], pal[2][2];
        #pragma unroll
        for (int i = 0; i < 2; ++i)
            #pragma unroll
            for (int kf = 0; kf < 2; ++kf) {
                int row = wr + 16 * i + l15;
                int byt = row * 128 + ((kf * 64 + g * 16) ^ ((row & 7) << 4));
                pah[i][kf] = *(const short8*)(smem + byt);
                pal[i][kf] = *(const short8*)(smem + 16384 + byt);
            }
        #pragma unroll
        for (int jd = 0; jd < 4; ++jd) {
            #pragma unroll
            for (int kf = 0; kf < 2; ++kf) {
                int d = 16 * jd + l15;
                int byt = 36864 + d * 128 + ((kf * 64 + g * 16) ^ ((d & 7) << 4));
                short8 vbh = *(const short8*)(smem + byt);
                short8 vbl = *(const short8*)(smem + 8192 + byt);
                #pragma unroll
                for (int i = 0; i < 2; ++i) {
                    ctx[i][jd] = __builtin_amdgcn_mfma_f32_16x16x32_bf16(pah[i][kf], vbh, ctx[i][jd], 0, 0, 0);
                    ctx[i][jd] = __builtin_amdgcn_mfma_f32_16x16x32_bf16(pah[i][kf], vbl, ctx[i][jd], 0, 0, 0);
                    ctx[i][jd] = __builtin_amdgcn_mfma_f32_16x16x32_bf16(pal[i][kf], vbh, ctx[i][jd], 0, 0, 0);
                }
            }
        }
    }

    if (MODE == 0) {
        __syncthreads();
        float* R = (float*)smem;   // [8 q][16 b][64 d] = 32 KB
        #pragma unroll
        for (int i = 0; i < 2; ++i)
            #pragma unroll
            for (int jd = 0; jd < 4; ++jd)
                #pragma unroll
                for (int q = 0; q < 4; ++q) {
                    int qa = 2 * w + i;
                    int bb = 4 * g + q;
                    int d  = 16 * jd + l15;
                    R[qa * 1024 + bb * 64 + d] = ctx[i][jd][q] * inv[i][q];
                }
        __syncthreads();
        for (int o = t; o < 1024; o += 256) {
            int bb = o >> 6, d = o & 63;
            float s = 0.f;
            #pragma unroll
            for (int qa = 0; qa < 8; ++qa) s += R[qa * 1024 + bb * 64 + d];
            s *= 0.125f;
            long long addr = (long long)(b0 + bb) * 512 + h * 64 + d;
            u16 hh = bf16_rn(s);
            Oh[addr] = hh;
            Ol[addr] = bf16_rn(s - bf16_f(hh));
        }
    } else {
        #pragma unroll
        for (int i = 0; i < 2; ++i)
            #pragma unroll
            for (int jd = 0; jd < 4; ++jd)
                #pragma unroll
                for (int q = 0; q < 4; ++q) {
                    int b = b0 + wr + 16 * i + 4 * g + q;
                    int d = 16 * jd + l15;
                    long long addr = (long long)b * 1024 + h * 64 + d;   // acat
                    float v = ctx[i][jd][q] * inv[i][q];
                    u16 hh = bf16_rn(v);
                    Oh[addr] = hh;
                    Ol[addr] = bf16_rn(v - bf16_f(hh));
                }
    }
}

// ============== merged attn launch: attn1 (1024) + attn2 (128) =============
__global__ __launch_bounds__(256, 2)
void attn_both(const u16* __restrict__ Q1h, const u16* __restrict__ Q1l,
               const u16* __restrict__ Q2h, const u16* __restrict__ Q2l,
               const u16* __restrict__ Kvh, const u16* __restrict__ Kvl,
               const u16* __restrict__ VTh, const u16* __restrict__ VTl,
               u16* __restrict__ cbh, u16* __restrict__ cbl,
               u16* __restrict__ ach, u16* __restrict__ acl)
{
    extern __shared__ char smem[];
    const int id = blockIdx.x;
    if (id < 1024) {
        attn_body<0>(smem, id >> 3, id & 7, Q1h, Q1l, Kvh, Kvl, VTh, VTl,
                     cbh, cbl);
    } else {
        const int j = id - 1024;
        attn_body<1>(smem, j >> 3, j & 7, Q2h, Q2l, Kvh, Kvl, VTh, VTl,
                     ach, acl);
    }
}

// ======== write+final launch: final GEMM (256 blocks) + out1 write =========
__global__ __launch_bounds__(256)
void write_final(const u16* __restrict__ ach, const u16* __restrict__ acl,
                 const u16* __restrict__ bch, const u16* __restrict__ bcl,
                 const float* __restrict__ bias2, float* __restrict__ out,
                 const float* __restrict__ mem, const float* __restrict__ uf,
                 float* __restrict__ out1)
{
    __shared__ u16 Ash[128][72];
    __shared__ u16 Asl[128][72];
    __shared__ u16 Bsh[64][72];
    __shared__ u16 Bsl[64][72];
    const int id = blockIdx.x;
    if (id < 256) {
        ZD dz = { ach, acl, bch, bcl, bias2, out, nullptr, nullptr,
                  2048, 1024, 1024, 1024, 1024, 0, 0, 1.0f };
        gemm_zd(dz, (id & 15) * 128, (id >> 4) * 64, Ash, Asl, Bsh, Bsl);
    } else {
        const f32x4* m4 = reinterpret_cast<const f32x4*>(mem);
        const f32x4* u4 = reinterpret_cast<const f32x4*>(uf);
        f32x4* o4 = reinterpret_cast<f32x4*>(out1);
        long long i0 = (long long)(id - 256) * 16384 + threadIdx.x;
        #pragma unroll 4
        for (int j = 0; j < 64; ++j) {
            long long i = i0 + j * 256;
            int e4 = (int)(i & 127);
            int m  = (int)((i >> 7) & 255);
            long long b = i >> 15;
            f32x4 a = m4[m * 128 + e4];
            f32x4 c = u4[b * 128 + e4];
            f32x4 rr = a + c;
            __builtin_nontemporal_store(rr, &o4[i]);
        }
    }
}

extern "C" void kernel_launch(void* const* d_in, const int* in_sizes, int n_in,
                              void* d_out, int out_size, void* d_ws, size_t ws_size,
                              hipStream_t stream)
{
    (void)in_sizes; (void)n_in; (void)out_size; (void)ws_size;
    const float* x     = (const float*)d_in[0];
    const float* mem   = (const float*)d_in[1];
    const float* enc_w = (const float*)d_in[2];
    const float* enc_b = (const float*)d_in[3];
    const float* blk_w = (const float*)d_in[4];
    const float* blk_b = (const float*)d_in[5];
    const float* in_w  = (const float*)d_in[6];
    const float* in_b  = (const float*)d_in[7];
    const float* out_w = (const float*)d_in[8];
    const float* out_b = (const float*)d_in[9];
    const float* dec_w = (const float*)d_in[10];
    const float* dec_b = (const float*)d_in[11];
    float* out = (float*)d_out;

    // ---------------- workspace carve-up (256B-aligned) --------------------
    char* p = (char*)d_ws;
    auto alloc = [&](size_t bytes) { char* q = p; p += (bytes + 255) & ~(size_t)255; return q; };
    u16* xh   = (u16*)alloc(2097152 * 2); u16* xl   = (u16*)alloc(2097152 * 2);
    u16* memh = (u16*)alloc(131072 * 2);  u16* meml = (u16*)alloc(131072 * 2);
    u16* ewh  = (u16*)alloc(524288 * 2);  u16* ewl  = (u16*)alloc(524288 * 2);
    u16* iwh  = (u16*)alloc(786432 * 2);  u16* iwl  = (u16*)alloc(786432 * 2);
    u16* owh  = (u16*)alloc(262144 * 2);  u16* owl  = (u16*)alloc(262144 * 2);
    u16* owTh = (u16*)alloc(262144 * 2);  u16* owTl = (u16*)alloc(262144 * 2);
    u16* dwh  = (u16*)alloc(524288 * 2);  u16* dwl  = (u16*)alloc(524288 * 2);
    u16* ench = (u16*)alloc(1048576 * 2); u16* encl = (u16*)alloc(1048576 * 2);
    u16* kvh  = (u16*)alloc(262144 * 2);  u16* kvl  = (u16*)alloc(262144 * 2);
    u16* vpTh = (u16*)alloc(131072 * 2);  u16* vpTl = (u16*)alloc(131072 * 2);
    float* bias1  = (float*)alloc(4096 * 4);
    float* bias2  = (float*)alloc(1024 * 4);
    float* biasuv = (float*)alloc(512 * 4);
    u16* cbh  = (u16*)alloc(1048576 * 2); u16* cbl  = (u16*)alloc(1048576 * 2);
    float* uf = (float*)alloc(1048576 * 4);
    u16* qp2h = (u16*)alloc(1048576 * 2); u16* qp2l = (u16*)alloc(1048576 * 2);
    u16* Wuvh = (u16*)alloc(262144 * 2);  u16* Wuvl = (u16*)alloc(262144 * 2);
    u16* ach  = (u16*)alloc(2097152 * 2); u16* acl  = (u16*)alloc(2097152 * 2);   // [2048][1024]
    u16* bch  = (u16*)alloc(1048576 * 2); u16* bcl  = (u16*)alloc(1048576 * 2);   // [1024][1024]

    // ------ big scratch in the not-yet-written updated_memory region -------
    float* out1 = out + 2097152;
    u16* bwTh = (u16*)out1;               // [8][512][512]
    u16* bwTl = bwTh + 2097152;
    u16* W1h  = bwTl + 2097152;           // [8][512][512]
    u16* W1l  = W1h + 2097152;
    u16* qp1h = W1l + 2097152;            // [8][2048][512]
    u16* qp1l = qp1h + 8388608;

    dim3 blk(256);

    // 1. prep: split + transposes + folded biases
    prep_all<<<dim3(4374), blk, 0, stream>>>(x, mem, enc_w, in_w, out_w, dec_w,
        blk_w, in_b, blk_b, out_b, dec_b,
        xh, xl, memh, meml, ewh, ewl, iwh, iwl, owh, owl, dwh, dwl,
        bwTh, bwTl, owTh, owTl, bias1, bias2, biasuv);

    // 2. z=16 batch: enc, W1 x8, Wuv, W2-dup x4, kv(wk), vpT(wv transposed)
    {
        ZPack<16> pk;
        pk.d[0] = { xh, xl, ewh, ewl, enc_b, nullptr, ench, encl,
                    2048, 1024, 1024, 512, 1024, 1, 1, 1.0f };
        for (int z = 0; z < 8; ++z)
            pk.d[1 + z] = { iwh, iwl, bwTh + (long long)z * 262144, bwTl + (long long)z * 262144,
                            nullptr, nullptr, W1h + (long long)z * 262144, W1l + (long long)z * 262144,
                            512, 512, 512, 512, 512, 0, 1, 1.0f };
        pk.d[9]  = { iwh + 1024 * 512, iwl + 1024 * 512, owTh, owTl, nullptr,
                     nullptr, Wuvh, Wuvl, 512, 512, 512, 512, 512, 0, 1, 1.0f };
        // W2 = dec_w@out_w written TWICE into bcat cols [0,512) and [512,1024)
        for (int s = 0; s < 2; ++s)
            for (int c = 0; c < 2; ++c)
                pk.d[10 + s * 2 + c] = { dwh + (long long)s * 262144, dwl + (long long)s * 262144,
                                         owTh, owTl, nullptr, nullptr,
                                         bch + (long long)s * 524288 + c * 512,
                                         bcl + (long long)s * 524288 + c * 512,
                                         512, 512, 512, 1024, 512, 0, 1, 1.0f };
        pk.d[14] = { memh, meml, iwh + 512 * 512, iwl + 512 * 512, in_b + 512,
                     nullptr, kvh, kvl, 256, 512, 512, 1024, 512, 0, 1, 1.0f };
        pk.d[15] = { memh, meml, iwh + 1024 * 512, iwl + 1024 * 512, in_b + 1024,
                     nullptr, vpTh, vpTl, 256, 512, 512, 256, 512, 0, 2, 1.0f };
        gemm_multi<16><<<dim3(16, 8, 16), blk, 0, stream>>>(pk);
    }
    // 3. qp1 x8 + qp2   (z=9, 0.125 folded)
    {
        ZPack<9> pk;
        for (int z = 0; z < 8; ++z)
            pk.d[z] = { ench, encl, W1h + (long long)z * 262144, W1l + (long long)z * 262144,
                        bias1 + z * 512, nullptr,
                        qp1h + (long long)z * 1048576, qp1l + (long long)z * 1048576,
                        2048, 512, 512, 512, 512, 0, 1, 0.125f };
        pk.d[8] = { ench, encl, iwh, iwl, in_b, nullptr, qp2h, qp2l,
                    2048, 512, 512, 512, 512, 0, 1, 0.125f };
        gemm_multi<9><<<dim3(16, 8, 9), blk, 0, stream>>>(pk);
    }
    // 4. attn1 (-> cb) + attn2 (-> acat cols 0..511), one launch
    attn_both<<<dim3(1152), blk, 73728, stream>>>(qp1h, qp1l, qp2h, qp2l,
        kvh, kvl, vpTh, vpTl, cbh, cbl, ach, acl);
    // 5. u (f32) + uvb (-> acat cols 512..1023), batched
    {
        ZPack<2> pk;
        pk.d[0] = { cbh, cbl, owh, owl, out_b, uf, nullptr, nullptr,
                    2048, 512, 512, 512, 512, 0, 0, 1.0f };
        pk.d[1] = { cbh, cbl, Wuvh, Wuvl, biasuv, nullptr, ach + 512, acl + 512,
                    2048, 512, 512, 1024, 512, 0, 1, 1.0f };
        gemm_multi<2><<<dim3(16, 8, 2), blk, 0, stream>>>(pk);
    }
    // 6. final GEMM (K=1024 concat) rides the 1.07 GB out1 write
    //    (out-region scratch qp1/W1/bwT dead after step 4)
    write_final<<<dim3(4352), blk, 0, stream>>>(ach, acl, bch, bcl, bias2, out,
        mem, uf, out1);
}

// Round 8
// 497.773 us; speedup vs baseline: 1.4239x; 1.4239x over previous
//
#include <hip/hip_runtime.h>
#include <math.h>

// ---------------------------------------------------------------------------
// MemoryAugmentedNetwork — R7: R6's 6-dispatch structure with the proven
// BK=32 GEMM core restored (R6's BK=64 halved occupancy -> 709us regression).
// Shapes: B=2048, IN=1024, E=512, M=256, NB=H=8, D=64
// Algebra (exact): shared K/V; mean->out_w commute; MHA2 collapse;
// W1=wq@blk_w; Wuv=wv@out_w (uvb = cb@Wuv^T + wv@out_b);
// final = [ctx2core | uvb] @ [W2 | W2]^T + bias2,  W2=dec_w@out_w.
// Numerics: split-bf16 (a=ah+al), C=AhBh+AhBl+AlBh, f32 accum.
// ---------------------------------------------------------------------------

typedef __attribute__((ext_vector_type(8))) short short8;
typedef __attribute__((ext_vector_type(4))) float f32x4;
typedef unsigned short u16;

__device__ inline u16 bf16_rn(float x) {
    unsigned u = __float_as_uint(x);
    unsigned r = (u + 0x7FFFu + ((u >> 16) & 1u)) >> 16;
    return (u16)r;
}
__device__ inline float bf16_f(u16 h) { return __uint_as_float(((unsigned)h) << 16); }

// ======================= prep: split + transpose + bias ====================
__global__ __launch_bounds__(256)
void prep_all(const float* __restrict__ x, const float* __restrict__ mm,
              const float* __restrict__ ew, const float* __restrict__ iw,
              const float* __restrict__ ow, const float* __restrict__ dw,
              const float* __restrict__ blk_w,
              const float* __restrict__ in_b, const float* __restrict__ blk_b,
              const float* __restrict__ out_b, const float* __restrict__ dec_b,
              u16* __restrict__ xh, u16* __restrict__ xl,
              u16* __restrict__ mh, u16* __restrict__ ml,
              u16* __restrict__ ewh, u16* __restrict__ ewl,
              u16* __restrict__ iwh, u16* __restrict__ iwl,
              u16* __restrict__ owh, u16* __restrict__ owl,
              u16* __restrict__ dwh, u16* __restrict__ dwl,
              u16* __restrict__ bwTh, u16* __restrict__ bwTl,
              u16* __restrict__ owTh, u16* __restrict__ owTl,
              float* __restrict__ bias1, float* __restrict__ bias2,
              float* __restrict__ bias_uv)
{
    __shared__ float T[32][33];
    const int id = blockIdx.x;
    const int t = threadIdx.x;
    if (id < 2304) {
        const int z = id >> 8, within = id & 255;
        const float* s; u16 *dh, *dl;
        if (z < 8) { s = blk_w + (long long)z * 262144;
                     dh = bwTh + (long long)z * 262144; dl = bwTl + (long long)z * 262144; }
        else       { s = ow; dh = owTh; dl = owTl; }
        const int c0 = (within & 15) * 32, r0 = (within >> 4) * 32;
        const int tx = t & 31, ty = t >> 5;
        #pragma unroll
        for (int rr = 0; rr < 4; ++rr)
            T[ty + rr * 8][tx] = s[(long long)(r0 + ty + rr * 8) * 512 + c0 + tx];
        __syncthreads();
        #pragma unroll
        for (int rr = 0; rr < 4; ++rr) {
            float v = T[tx][ty + rr * 8];
            long long o = (long long)(c0 + ty + rr * 8) * 512 + r0 + tx;
            u16 hh = bf16_rn(v);
            dh[o] = hh; dl[o] = bf16_rn(v - bf16_f(hh));
        }
    } else if (id < 2326) {
        int idx = (id - 2304) * 256 + t;   // 5632
        if (idx < 4096) {
            int n = idx >> 9, f = idx & 511;
            const float* wr_ = iw + (long long)f * 512;
            const float* bb  = blk_b + n * 512;
            float s = in_b[f];
            for (int o = 0; o < 512; ++o) s += wr_[o] * bb[o];
            bias1[idx] = s;
        } else if (idx < 5120) {
            int i = idx - 4096;
            const float* dr = dw + (long long)i * 512;
            float s = dec_b[i];
            for (int f = 0; f < 512; ++f) s += dr[f] * out_b[f];
            bias2[i] = s;
        } else if (idx < 5632) {
            int f = idx - 5120;
            const float* wv = iw + (long long)(1024 + f) * 512;
            float s = 0.f;
            for (int e = 0; e < 512; ++e) s += wv[e] * out_b[e];
            bias_uv[f] = s;
        }
    } else {
        const long long total = 1081344;
        const long long stride = 2048LL * 256;
        for (long long i = (long long)(id - 2326) * 256 + t; i < total; i += stride) {
            const float* src; u16 *hi, *lo; long long j;
            if (i < 524288)      { src = x;  hi = xh;  lo = xl;  j = i; }
            else if (i < 557056) { src = mm; hi = mh;  lo = ml;  j = i - 524288; }
            else if (i < 688128) { src = ew; hi = ewh; lo = ewl; j = i - 557056; }
            else if (i < 884736) { src = iw; hi = iwh; lo = iwl; j = i - 688128; }
            else if (i < 950272) { src = ow; hi = owh; lo = owl; j = i - 884736; }
            else                 { src = dw; hi = dwh; lo = dwl; j = i - 950272; }
            float4 v = reinterpret_cast<const float4*>(src)[j];
            u16 h0 = bf16_rn(v.x), h1 = bf16_rn(v.y), h2 = bf16_rn(v.z), h3 = bf16_rn(v.w);
            ushort4 hv = {h0, h1, h2, h3};
            ushort4 lv = {bf16_rn(v.x - bf16_f(h0)), bf16_rn(v.y - bf16_f(h1)),
                          bf16_rn(v.z - bf16_f(h2)), bf16_rn(v.w - bf16_f(h3))};
            reinterpret_cast<ushort4*>(hi)[j] = hv;
            reinterpret_cast<ushort4*>(lo)[j] = lv;
        }
    }
}

// ===================== generalized descriptor GEMM core (BK=32) ============
// C = act( (A @ B^T + bias) * scale ); omode 0=f32, 1=planes,
// 2=planes transposed (C[col*ldc+row]).  BM=128 BN=64 BK=32, 4 waves.
// LDS 30720 B -> 5 blocks/CU.
struct ZD {
    const u16 *Ah, *Al, *Bh, *Bl;
    const float* bias;
    float* Cf; u16 *Ch, *Cl;
    int M, lda, ldb, ldc, K, act, omode;
    float scale;
};
template<int NZ> struct ZPack { ZD d[NZ]; };

__device__ __forceinline__ void gemm_zd(const ZD& dz, int m0, int n0,
    u16 (*Ash)[40], u16 (*Asl)[40], u16 (*Bsh)[40], u16 (*Bsl)[40])
{
    const int t  = threadIdx.x;
    const int r  = t >> 2;
    const int ck = (t & 3) << 3;
    const int lane = t & 63;
    const int wid  = t >> 6;
    const int wr = (wid >> 1) * 64;
    const int wc = (wid & 1) * 32;
    const int lr = lane & 15;
    const int lk = (lane >> 4) << 3;

    f32x4 acc[4][2];
    const f32x4 zero = {0.f, 0.f, 0.f, 0.f};
    #pragma unroll
    for (int i = 0; i < 4; ++i)
        #pragma unroll
        for (int j = 0; j < 2; ++j) acc[i][j] = zero;

    const long long arow0 = (long long)(m0 + r) * dz.lda;
    const long long arow1 = (long long)(m0 + r + 64) * dz.lda;
    const long long brow  = (long long)(n0 + r) * dz.ldb;

    for (int k0 = 0; k0 < dz.K; k0 += 32) {
        int4 vah0 = *reinterpret_cast<const int4*>(dz.Ah + arow0 + k0 + ck);
        int4 vah1 = *reinterpret_cast<const int4*>(dz.Ah + arow1 + k0 + ck);
        int4 val0 = *reinterpret_cast<const int4*>(dz.Al + arow0 + k0 + ck);
        int4 val1 = *reinterpret_cast<const int4*>(dz.Al + arow1 + k0 + ck);
        int4 vbh  = *reinterpret_cast<const int4*>(dz.Bh + brow  + k0 + ck);
        int4 vbl  = *reinterpret_cast<const int4*>(dz.Bl + brow  + k0 + ck);
        __syncthreads();
        *reinterpret_cast<int4*>(&Ash[r][ck])      = vah0;
        *reinterpret_cast<int4*>(&Ash[r + 64][ck]) = vah1;
        *reinterpret_cast<int4*>(&Asl[r][ck])      = val0;
        *reinterpret_cast<int4*>(&Asl[r + 64][ck]) = val1;
        *reinterpret_cast<int4*>(&Bsh[r][ck])      = vbh;
        *reinterpret_cast<int4*>(&Bsl[r][ck])      = vbl;
        __syncthreads();

        short8 fah[4], fal[4], fbh[2], fbl[2];
        #pragma unroll
        for (int i = 0; i < 4; ++i) {
            fah[i] = *reinterpret_cast<const short8*>(&Ash[wr + i * 16 + lr][lk]);
            fal[i] = *reinterpret_cast<const short8*>(&Asl[wr + i * 16 + lr][lk]);
        }
        #pragma unroll
        for (int j = 0; j < 2; ++j) {
            fbh[j] = *reinterpret_cast<const short8*>(&Bsh[wc + j * 16 + lr][lk]);
            fbl[j] = *reinterpret_cast<const short8*>(&Bsl[wc + j * 16 + lr][lk]);
        }
        #pragma unroll
        for (int i = 0; i < 4; ++i)
            #pragma unroll
            for (int j = 0; j < 2; ++j) {
                acc[i][j] = __builtin_amdgcn_mfma_f32_16x16x32_bf16(fah[i], fbh[j], acc[i][j], 0, 0, 0);
                acc[i][j] = __builtin_amdgcn_mfma_f32_16x16x32_bf16(fah[i], fbl[j], acc[i][j], 0, 0, 0);
                acc[i][j] = __builtin_amdgcn_mfma_f32_16x16x32_bf16(fal[i], fbh[j], acc[i][j], 0, 0, 0);
            }
    }

    #pragma unroll
    for (int j = 0; j < 2; ++j) {
        const int col = n0 + wc + j * 16 + lr;
        const float bv = dz.bias ? dz.bias[col] : 0.f;
        #pragma unroll
        for (int i = 0; i < 4; ++i) {
            #pragma unroll
            for (int q = 0; q < 4; ++q) {
                const int row = m0 + wr + i * 16 + ((lane >> 4) << 2) + q;
                float v = (acc[i][j][q] + bv) * dz.scale;
                if (dz.act) v = tanhf(v);
                if (dz.omode == 0) {
                    dz.Cf[(long long)row * dz.ldc + col] = v;
                } else {
                    long long off = (dz.omode == 1)
                        ? (long long)row * dz.ldc + col
                        : (long long)col * dz.ldc + row;
                    u16 h = bf16_rn(v);
                    dz.Ch[off] = h;
                    dz.Cl[off] = bf16_rn(v - bf16_f(h));
                }
            }
        }
    }
}

template<int NZ>
__global__ __launch_bounds__(256)
void gemm_multi(ZPack<NZ> pk)
{
    __shared__ u16 Ash[128][40];
    __shared__ u16 Asl[128][40];
    __shared__ u16 Bsh[64][40];
    __shared__ u16 Bsl[64][40];
    const ZD dz = pk.d[blockIdx.z];
    const int m0 = blockIdx.x * 128;
    if (m0 >= dz.M) return;
    gemm_zd(dz, m0, blockIdx.y * 64, Ash, Asl, Bsh, Bsl);
}

// ======================= fused attention (device body) =====================
// 128 q-rows x 256 keys x 64 d; K in 2 halves; PV in 4 key-quarters; 72KB LDS.
// MODE 0: Q = qp1 slice, rows=q*16+bb; epilogue q-mean -> cb (ldc 512).
// MODE 1: Q = qp2; epilogue -> acat (ldc 1024, cols 0..511), NO uv term.
template<int MODE>
__device__ __forceinline__ void attn_body(char* smem, int bxblk, int h,
    const u16* __restrict__ Qph, const u16* __restrict__ Qpl,
    const u16* __restrict__ Kvh, const u16* __restrict__ Kvl,
    const u16* __restrict__ VTh, const u16* __restrict__ VTl,
    u16* __restrict__ Oh, u16* __restrict__ Ol)
{
    const int t = threadIdx.x;
    const int lane = t & 63, w = t >> 6;
    const int l15 = lane & 15, g = lane >> 4;
    const int wr = w * 32;
    const int b0 = bxblk * (MODE == 0 ? 16 : 128);

    u16* Qs = (u16*)smem;            // [2][128][72] = 36864 B
    char* KsB = smem + 36864;        // [2][128][72] u16 = 36864 B

    for (int c = t; c < 2048; c += 256) {
        int plane = c >> 10, rem = c & 1023;
        int row = rem >> 3, seg = rem & 7;
        const u16* src = plane ? Qpl : Qph;
        long long addr;
        if (MODE == 0) {
            int q = row >> 4, bb = row & 15;
            addr = ((long long)q * 2048 + b0 + bb) * 512 + h * 64 + seg * 8;
        } else {
            addr = (long long)(b0 + row) * 512 + h * 64 + seg * 8;
        }
        *(int4*)(&Qs[plane * 9216 + row * 72 + seg * 8]) = *(const int4*)(src + addr);
    }

    f32x4 sacc[2][16];
    const f32x4 zero = {0.f, 0.f, 0.f, 0.f};
    #pragma unroll
    for (int i = 0; i < 2; ++i)
        #pragma unroll
        for (int j = 0; j < 16; ++j) sacc[i][j] = zero;

    short8 qfh[2][2], qfl[2][2];

    for (int kh = 0; kh < 2; ++kh) {
        if (kh) __syncthreads();
        for (int c = t; c < 2048; c += 256) {
            int plane = c >> 10, rem = c & 1023;
            int key = rem >> 3, seg = rem & 7;
            const u16* src = plane ? Kvl : Kvh;
            *(int4*)(KsB + plane * 18432 + key * 144 + seg * 16) =
                *(const int4*)(src + (long long)(kh * 128 + key) * 1024 + h * 64 + seg * 8);
        }
        __syncthreads();
        if (kh == 0) {
            #pragma unroll
            for (int i = 0; i < 2; ++i)
                #pragma unroll
                for (int kf = 0; kf < 2; ++kf) {
                    int ro = (wr + 16 * i + l15) * 72 + kf * 32 + g * 8;
                    qfh[i][kf] = *(const short8*)(&Qs[ro]);
                    qfl[i][kf] = *(const short8*)(&Qs[9216 + ro]);
                }
        }
        #pragma unroll
        for (int j = 0; j < 8; ++j) {
            int jg = kh * 8 + j;
            #pragma unroll
            for (int kf = 0; kf < 2; ++kf) {
                const char* kb = KsB + (j * 16 + l15) * 144 + (kf * 32 + g * 8) * 2;
                short8 kbh = *(const short8*)(kb);
                short8 kbl = *(const short8*)(kb + 18432);
                #pragma unroll
                for (int i = 0; i < 2; ++i) {
                    sacc[i][jg] = __builtin_amdgcn_mfma_f32_16x16x32_bf16(qfh[i][kf], kbh, sacc[i][jg], 0, 0, 0);
                    sacc[i][jg] = __builtin_amdgcn_mfma_f32_16x16x32_bf16(qfh[i][kf], kbl, sacc[i][jg], 0, 0, 0);
                    sacc[i][jg] = __builtin_amdgcn_mfma_f32_16x16x32_bf16(qfl[i][kf], kbh, sacc[i][jg], 0, 0, 0);
                }
            }
        }
    }

    float inv[2][4];
    #pragma unroll
    for (int i = 0; i < 2; ++i)
        #pragma unroll
        for (int q = 0; q < 4; ++q) {
            float m = -1e30f;
            #pragma unroll
            for (int j = 0; j < 16; ++j) m = fmaxf(m, sacc[i][j][q]);
            #pragma unroll
            for (int off = 1; off <= 8; off <<= 1) m = fmaxf(m, __shfl_xor(m, off, 64));
            #pragma unroll
            for (int j = 0; j < 16; ++j) sacc[i][j][q] = __expf(sacc[i][j][q] - m);
            float s = 0.f;
            #pragma unroll
            for (int j = 0; j < 16; ++j) s += sacc[i][j][q];
            #pragma unroll
            for (int off = 1; off <= 8; off <<= 1) s += __shfl_xor(s, off, 64);
            inv[i][q] = 1.0f / s;
        }

    f32x4 ctx[2][4];
    #pragma unroll
    for (int i = 0; i < 2; ++i)
        #pragma unroll
        for (int jd = 0; jd < 4; ++jd) ctx[i][jd] = zero;

    for (int qt = 0; qt < 4; ++qt) {
        __syncthreads();
        #pragma unroll
        for (int i = 0; i < 2; ++i)
            #pragma unroll
            for (int jj = 0; jj < 4; ++jj) {
                int jg = qt * 4 + jj;
                #pragma unroll
                for (int q = 0; q < 4; ++q) {
                    int row = wr + 16 * i + 4 * g + q;
                    int key = jj * 16 + l15;
                    float pv = sacc[i][jg][q];
                    u16 ph = bf16_rn(pv);
                    u16 pl = bf16_rn(pv - bf16_f(ph));
                    int byt = row * 128 + ((key * 2) ^ ((row & 7) << 4));
                    *(u16*)(smem + byt) = ph;
                    *(u16*)(smem + 16384 + byt) = pl;
                }
            }
        for (int c = t; c < 1024; c += 256) {
            int plane = c >> 9, rem = c & 511;
            int d = rem >> 3, seg = rem & 7;
            const u16* src = plane ? VTl : VTh;
            int4 v = *(const int4*)(src + (long long)h * 16384 + d * 256 + qt * 64 + seg * 8);
            int byt = 36864 + plane * 8192 + d * 128 + ((seg * 16) ^ ((d & 7) << 4));
            *(int4*)(smem + byt) = v;
        }
        __syncthreads();

        short8 pah[2][2], pal[2][2];
        #pragma unroll
        for (int i = 0; i < 2; ++i)
            #pragma unroll
            for (int kf = 0; kf < 2; ++kf) {
                int row = wr + 16 * i + l15;
                int byt = row * 128 + ((kf * 64 + g * 16) ^ ((row & 7) << 4));
                pah[i][kf] = *(const short8*)(smem + byt);
                pal[i][kf] = *(const short8*)(smem + 16384 + byt);
            }
        #pragma unroll
        for (int jd = 0; jd < 4; ++jd) {
            #pragma unroll
            for (int kf = 0; kf < 2; ++kf) {
                int d = 16 * jd + l15;
                int byt = 36864 + d * 128 + ((kf * 64 + g * 16) ^ ((d & 7) << 4));
                short8 vbh = *(const short8*)(smem + byt);
                short8 vbl = *(const short8*)(smem + 8192 + byt);
                #pragma unroll
                for (int i = 0; i < 2; ++i) {
                    ctx[i][jd] = __builtin_amdgcn_mfma_f32_16x16x32_bf16(pah[i][kf], vbh, ctx[i][jd], 0, 0, 0);
                    ctx[i][jd] = __builtin_amdgcn_mfma_f32_16x16x32_bf16(pah[i][kf], vbl, ctx[i][jd], 0, 0, 0);
                    ctx[i][jd] = __builtin_amdgcn_mfma_f32_16x16x32_bf16(pal[i][kf], vbh, ctx[i][jd], 0, 0, 0);
                }
            }
        }
    }

    if (MODE == 0) {
        __syncthreads();
        float* R = (float*)smem;   // [8 q][16 b][64 d] = 32 KB
        #pragma unroll
        for (int i = 0; i < 2; ++i)
            #pragma unroll
            for (int jd = 0; jd < 4; ++jd)
                #pragma unroll
                for (int q = 0; q < 4; ++q) {
                    int qa = 2 * w + i;
                    int bb = 4 * g + q;
                    int d  = 16 * jd + l15;
                    R[qa * 1024 + bb * 64 + d] = ctx[i][jd][q] * inv[i][q];
                }
        __syncthreads();
        for (int o = t; o < 1024; o += 256) {
            int bb = o >> 6, d = o & 63;
            float s = 0.f;
            #pragma unroll
            for (int qa = 0; qa < 8; ++qa) s += R[qa * 1024 + bb * 64 + d];
            s *= 0.125f;
            long long addr = (long long)(b0 + bb) * 512 + h * 64 + d;
            u16 hh = bf16_rn(s);
            Oh[addr] = hh;
            Ol[addr] = bf16_rn(s - bf16_f(hh));
        }
    } else {
        #pragma unroll
        for (int i = 0; i < 2; ++i)
            #pragma unroll
            for (int jd = 0; jd < 4; ++jd)
                #pragma unroll
                for (int q = 0; q < 4; ++q) {
                    int b = b0 + wr + 16 * i + 4 * g + q;
                    int d = 16 * jd + l15;
                    long long addr = (long long)b * 1024 + h * 64 + d;   // acat
                    float v = ctx[i][jd][q] * inv[i][q];
                    u16 hh = bf16_rn(v);
                    Oh[addr] = hh;
                    Ol[addr] = bf16_rn(v - bf16_f(hh));
                }
    }
}

// ============== merged attn launch: attn1 (1024) + attn2 (128) =============
__global__ __launch_bounds__(256, 2)
void attn_both(const u16* __restrict__ Q1h, const u16* __restrict__ Q1l,
               const u16* __restrict__ Q2h, const u16* __restrict__ Q2l,
               const u16* __restrict__ Kvh, const u16* __restrict__ Kvl,
               const u16* __restrict__ VTh, const u16* __restrict__ VTl,
               u16* __restrict__ cbh, u16* __restrict__ cbl,
               u16* __restrict__ ach, u16* __restrict__ acl)
{
    extern __shared__ char smem[];
    const int id = blockIdx.x;
    if (id < 1024) {
        attn_body<0>(smem, id >> 3, id & 7, Q1h, Q1l, Kvh, Kvl, VTh, VTl,
                     cbh, cbl);
    } else {
        const int j = id - 1024;
        attn_body<1>(smem, j >> 3, j & 7, Q2h, Q2l, Kvh, Kvl, VTh, VTl,
                     ach, acl);
    }
}

// ======== write+final launch: final GEMM (256 blocks) + out1 write =========
__global__ __launch_bounds__(256)
void write_final(const u16* __restrict__ ach, const u16* __restrict__ acl,
                 const u16* __restrict__ bch, const u16* __restrict__ bcl,
                 const float* __restrict__ bias2, float* __restrict__ out,
                 const float* __restrict__ mem, const float* __restrict__ uf,
                 float* __restrict__ out1)
{
    __shared__ u16 Ash[128][40];
    __shared__ u16 Asl[128][40];
    __shared__ u16 Bsh[64][40];
    __shared__ u16 Bsl[64][40];
    const int id = blockIdx.x;
    if (id < 256) {
        ZD dz = { ach, acl, bch, bcl, bias2, out, nullptr, nullptr,
                  2048, 1024, 1024, 1024, 1024, 0, 0, 1.0f };
        gemm_zd(dz, (id & 15) * 128, (id >> 4) * 64, Ash, Asl, Bsh, Bsl);
    } else {
        const f32x4* m4 = reinterpret_cast<const f32x4*>(mem);
        const f32x4* u4 = reinterpret_cast<const f32x4*>(uf);
        f32x4* o4 = reinterpret_cast<f32x4*>(out1);
        long long i0 = (long long)(id - 256) * 16384 + threadIdx.x;
        #pragma unroll 4
        for (int j = 0; j < 64; ++j) {
            long long i = i0 + j * 256;
            int e4 = (int)(i & 127);
            int m  = (int)((i >> 7) & 255);
            long long b = i >> 15;
            f32x4 a = m4[m * 128 + e4];
            f32x4 c = u4[b * 128 + e4];
            f32x4 rr = a + c;
            __builtin_nontemporal_store(rr, &o4[i]);
        }
    }
}

extern "C" void kernel_launch(void* const* d_in, const int* in_sizes, int n_in,
                              void* d_out, int out_size, void* d_ws, size_t ws_size,
                              hipStream_t stream)
{
    (void)in_sizes; (void)n_in; (void)out_size; (void)ws_size;
    const float* x     = (const float*)d_in[0];
    const float* mem   = (const float*)d_in[1];
    const float* enc_w = (const float*)d_in[2];
    const float* enc_b = (const float*)d_in[3];
    const float* blk_w = (const float*)d_in[4];
    const float* blk_b = (const float*)d_in[5];
    const float* in_w  = (const float*)d_in[6];
    const float* in_b  = (const float*)d_in[7];
    const float* out_w = (const float*)d_in[8];
    const float* out_b = (const float*)d_in[9];
    const float* dec_w = (const float*)d_in[10];
    const float* dec_b = (const float*)d_in[11];
    float* out = (float*)d_out;

    // ---------------- workspace carve-up (256B-aligned) --------------------
    char* p = (char*)d_ws;
    auto alloc = [&](size_t bytes) { char* q = p; p += (bytes + 255) & ~(size_t)255; return q; };
    u16* xh   = (u16*)alloc(2097152 * 2); u16* xl   = (u16*)alloc(2097152 * 2);
    u16* memh = (u16*)alloc(131072 * 2);  u16* meml = (u16*)alloc(131072 * 2);
    u16* ewh  = (u16*)alloc(524288 * 2);  u16* ewl  = (u16*)alloc(524288 * 2);
    u16* iwh  = (u16*)alloc(786432 * 2);  u16* iwl  = (u16*)alloc(786432 * 2);
    u16* owh  = (u16*)alloc(262144 * 2);  u16* owl  = (u16*)alloc(262144 * 2);
    u16* owTh = (u16*)alloc(262144 * 2);  u16* owTl = (u16*)alloc(262144 * 2);
    u16* dwh  = (u16*)alloc(524288 * 2);  u16* dwl  = (u16*)alloc(524288 * 2);
    u16* ench = (u16*)alloc(1048576 * 2); u16* encl = (u16*)alloc(1048576 * 2);
    u16* kvh  = (u16*)alloc(262144 * 2);  u16* kvl  = (u16*)alloc(262144 * 2);
    u16* vpTh = (u16*)alloc(131072 * 2);  u16* vpTl = (u16*)alloc(131072 * 2);
    float* bias1  = (float*)alloc(4096 * 4);
    float* bias2  = (float*)alloc(1024 * 4);
    float* biasuv = (float*)alloc(512 * 4);
    u16* cbh  = (u16*)alloc(1048576 * 2); u16* cbl  = (u16*)alloc(1048576 * 2);
    float* uf = (float*)alloc(1048576 * 4);
    u16* qp2h = (u16*)alloc(1048576 * 2); u16* qp2l = (u16*)alloc(1048576 * 2);
    u16* Wuvh = (u16*)alloc(262144 * 2);  u16* Wuvl = (u16*)alloc(262144 * 2);
    u16* ach  = (u16*)alloc(2097152 * 2); u16* acl  = (u16*)alloc(2097152 * 2);   // [2048][1024]
    u16* bch  = (u16*)alloc(1048576 * 2); u16* bcl  = (u16*)alloc(1048576 * 2);   // [1024][1024]

    // ------ big scratch in the not-yet-written updated_memory region -------
    float* out1 = out + 2097152;
    u16* bwTh = (u16*)out1;               // [8][512][512]
    u16* bwTl = bwTh + 2097152;
    u16* W1h  = bwTl + 2097152;           // [8][512][512]
    u16* W1l  = W1h + 2097152;
    u16* qp1h = W1l + 2097152;            // [8][2048][512]
    u16* qp1l = qp1h + 8388608;

    dim3 blk(256);

    // 1. prep: split + transposes + folded biases
    prep_all<<<dim3(4374), blk, 0, stream>>>(x, mem, enc_w, in_w, out_w, dec_w,
        blk_w, in_b, blk_b, out_b, dec_b,
        xh, xl, memh, meml, ewh, ewl, iwh, iwl, owh, owl, dwh, dwl,
        bwTh, bwTl, owTh, owTl, bias1, bias2, biasuv);

    // 2. z=16 batch: enc, W1 x8, Wuv, W2-dup x4, kv(wk), vpT(wv transposed)
    {
        ZPack<16> pk;
        pk.d[0] = { xh, xl, ewh, ewl, enc_b, nullptr, ench, encl,
                    2048, 1024, 1024, 512, 1024, 1, 1, 1.0f };
        for (int z = 0; z < 8; ++z)
            pk.d[1 + z] = { iwh, iwl, bwTh + (long long)z * 262144, bwTl + (long long)z * 262144,
                            nullptr, nullptr, W1h + (long long)z * 262144, W1l + (long long)z * 262144,
                            512, 512, 512, 512, 512, 0, 1, 1.0f };
        pk.d[9]  = { iwh + 1024 * 512, iwl + 1024 * 512, owTh, owTl, nullptr,
                     nullptr, Wuvh, Wuvl, 512, 512, 512, 512, 512, 0, 1, 1.0f };
        // W2 = dec_w@out_w written TWICE into bcat cols [0,512) and [512,1024)
        for (int s = 0; s < 2; ++s)
            for (int c = 0; c < 2; ++c)
                pk.d[10 + s * 2 + c] = { dwh + (long long)s * 262144, dwl + (long long)s * 262144,
                                         owTh, owTl, nullptr, nullptr,
                                         bch + (long long)s * 524288 + c * 512,
                                         bcl + (long long)s * 524288 + c * 512,
                                         512, 512, 512, 1024, 512, 0, 1, 1.0f };
        pk.d[14] = { memh, meml, iwh + 512 * 512, iwl + 512 * 512, in_b + 512,
                     nullptr, kvh, kvl, 256, 512, 512, 1024, 512, 0, 1, 1.0f };
        pk.d[15] = { memh, meml, iwh + 1024 * 512, iwl + 1024 * 512, in_b + 1024,
                     nullptr, vpTh, vpTl, 256, 512, 512, 256, 512, 0, 2, 1.0f };
        gemm_multi<16><<<dim3(16, 8, 16), blk, 0, stream>>>(pk);
    }
    // 3. qp1 x8 + qp2   (z=9, 0.125 folded)
    {
        ZPack<9> pk;
        for (int z = 0; z < 8; ++z)
            pk.d[z] = { ench, encl, W1h + (long long)z * 262144, W1l + (long long)z * 262144,
                        bias1 + z * 512, nullptr,
                        qp1h + (long long)z * 1048576, qp1l + (long long)z * 1048576,
                        2048, 512, 512, 512, 512, 0, 1, 0.125f };
        pk.d[8] = { ench, encl, iwh, iwl, in_b, nullptr, qp2h, qp2l,
                    2048, 512, 512, 512, 512, 0, 1, 0.125f };
        gemm_multi<9><<<dim3(16, 8, 9), blk, 0, stream>>>(pk);
    }
    // 4. attn1 (-> cb) + attn2 (-> acat cols 0..511), one launch
    attn_both<<<dim3(1152), blk, 73728, stream>>>(qp1h, qp1l, qp2h, qp2l,
        kvh, kvl, vpTh, vpTl, cbh, cbl, ach, acl);
    // 5. u (f32) + uvb (-> acat cols 512..1023), batched
    {
        ZPack<2> pk;
        pk.d[0] = { cbh, cbl, owh, owl, out_b, uf, nullptr, nullptr,
                    2048, 512, 512, 512, 512, 0, 0, 1.0f };
        pk.d[1] = { cbh, cbl, Wuvh, Wuvl, biasuv, nullptr, ach + 512, acl + 512,
                    2048, 512, 512, 1024, 512, 0, 1, 1.0f };
        gemm_multi<2><<<dim3(16, 8, 2), blk, 0, stream>>>(pk);
    }
    // 6. final GEMM (K=1024 concat) rides the 1.07 GB out1 write
    //    (out-region scratch qp1/W1/bwT dead after step 4)
    write_final<<<dim3(4352), blk, 0, stream>>>(ach, acl, bch, bcl, bias2, out,
        mem, uf, out1);
}

// Round 9
// 487.698 us; speedup vs baseline: 1.4533x; 1.0207x over previous
//
#include <hip/hip_runtime.h>
#include <math.h>

// ---------------------------------------------------------------------------
// MemoryAugmentedNetwork — R8: R7 + global_load_lds GEMM staging.
// GEMM core: BK=32, unpadded LDS [128][32]/[64][32] (24 KB, 6 blocks/CU),
// 6x global_load_lds(16B) per K-tile (async DMA, no VGPR roundtrip).
// Shapes: B=2048, IN=1024, E=512, M=256, NB=H=8, D=64
// Algebra (exact): shared K/V; mean->out_w commute; MHA2 collapse;
// W1=wq@blk_w; Wuv=wv@out_w (uvb = cb@Wuv^T + wv@out_b);
// final = [ctx2core | uvb] @ [W2 | W2]^T + bias2,  W2=dec_w@out_w.
// Numerics: split-bf16 (a=ah+al), C=AhBh+AhBl+AlBh, f32 accum.
// ---------------------------------------------------------------------------

typedef __attribute__((ext_vector_type(8))) short short8;
typedef __attribute__((ext_vector_type(4))) float f32x4;
typedef unsigned short u16;

#define GLOAD16(gp, lp)                                                        \
    __builtin_amdgcn_global_load_lds(                                          \
        (const __attribute__((address_space(1))) void*)(gp),                   \
        (__attribute__((address_space(3))) void*)(lp), 16, 0, 0)

__device__ inline u16 bf16_rn(float x) {
    unsigned u = __float_as_uint(x);
    unsigned r = (u + 0x7FFFu + ((u >> 16) & 1u)) >> 16;
    return (u16)r;
}
__device__ inline float bf16_f(u16 h) { return __uint_as_float(((unsigned)h) << 16); }

// ======================= prep: split + transpose + bias ====================
__global__ __launch_bounds__(256)
void prep_all(const float* __restrict__ x, const float* __restrict__ mm,
              const float* __restrict__ ew, const float* __restrict__ iw,
              const float* __restrict__ ow, const float* __restrict__ dw,
              const float* __restrict__ blk_w,
              const float* __restrict__ in_b, const float* __restrict__ blk_b,
              const float* __restrict__ out_b, const float* __restrict__ dec_b,
              u16* __restrict__ xh, u16* __restrict__ xl,
              u16* __restrict__ mh, u16* __restrict__ ml,
              u16* __restrict__ ewh, u16* __restrict__ ewl,
              u16* __restrict__ iwh, u16* __restrict__ iwl,
              u16* __restrict__ owh, u16* __restrict__ owl,
              u16* __restrict__ dwh, u16* __restrict__ dwl,
              u16* __restrict__ bwTh, u16* __restrict__ bwTl,
              u16* __restrict__ owTh, u16* __restrict__ owTl,
              float* __restrict__ bias1, float* __restrict__ bias2,
              float* __restrict__ bias_uv)
{
    __shared__ float T[32][33];
    const int id = blockIdx.x;
    const int t = threadIdx.x;
    if (id < 2304) {
        const int z = id >> 8, within = id & 255;
        const float* s; u16 *dh, *dl;
        if (z < 8) { s = blk_w + (long long)z * 262144;
                     dh = bwTh + (long long)z * 262144; dl = bwTl + (long long)z * 262144; }
        else       { s = ow; dh = owTh; dl = owTl; }
        const int c0 = (within & 15) * 32, r0 = (within >> 4) * 32;
        const int tx = t & 31, ty = t >> 5;
        #pragma unroll
        for (int rr = 0; rr < 4; ++rr)
            T[ty + rr * 8][tx] = s[(long long)(r0 + ty + rr * 8) * 512 + c0 + tx];
        __syncthreads();
        #pragma unroll
        for (int rr = 0; rr < 4; ++rr) {
            float v = T[tx][ty + rr * 8];
            long long o = (long long)(c0 + ty + rr * 8) * 512 + r0 + tx;
            u16 hh = bf16_rn(v);
            dh[o] = hh; dl[o] = bf16_rn(v - bf16_f(hh));
        }
    } else if (id < 2326) {
        int idx = (id - 2304) * 256 + t;   // 5632
        if (idx < 4096) {
            int n = idx >> 9, f = idx & 511;
            const float* wr_ = iw + (long long)f * 512;
            const float* bb  = blk_b + n * 512;
            float s = in_b[f];
            for (int o = 0; o < 512; ++o) s += wr_[o] * bb[o];
            bias1[idx] = s;
        } else if (idx < 5120) {
            int i = idx - 4096;
            const float* dr = dw + (long long)i * 512;
            float s = dec_b[i];
            for (int f = 0; f < 512; ++f) s += dr[f] * out_b[f];
            bias2[i] = s;
        } else if (idx < 5632) {
            int f = idx - 5120;
            const float* wv = iw + (long long)(1024 + f) * 512;
            float s = 0.f;
            for (int e = 0; e < 512; ++e) s += wv[e] * out_b[e];
            bias_uv[f] = s;
        }
    } else {
        const long long total = 1081344;
        const long long stride = 2048LL * 256;
        for (long long i = (long long)(id - 2326) * 256 + t; i < total; i += stride) {
            const float* src; u16 *hi, *lo; long long j;
            if (i < 524288)      { src = x;  hi = xh;  lo = xl;  j = i; }
            else if (i < 557056) { src = mm; hi = mh;  lo = ml;  j = i - 524288; }
            else if (i < 688128) { src = ew; hi = ewh; lo = ewl; j = i - 557056; }
            else if (i < 884736) { src = iw; hi = iwh; lo = iwl; j = i - 688128; }
            else if (i < 950272) { src = ow; hi = owh; lo = owl; j = i - 884736; }
            else                 { src = dw; hi = dwh; lo = dwl; j = i - 950272; }
            float4 v = reinterpret_cast<const float4*>(src)[j];
            u16 h0 = bf16_rn(v.x), h1 = bf16_rn(v.y), h2 = bf16_rn(v.z), h3 = bf16_rn(v.w);
            ushort4 hv = {h0, h1, h2, h3};
            ushort4 lv = {bf16_rn(v.x - bf16_f(h0)), bf16_rn(v.y - bf16_f(h1)),
                          bf16_rn(v.z - bf16_f(h2)), bf16_rn(v.w - bf16_f(h3))};
            reinterpret_cast<ushort4*>(hi)[j] = hv;
            reinterpret_cast<ushort4*>(lo)[j] = lv;
        }
    }
}

// ========== generalized descriptor GEMM core (BK=32, global_load_lds) ======
// C = act( (A @ B^T + bias) * scale ); omode 0=f32, 1=planes,
// 2=planes transposed (C[col*ldc+row]).  BM=128 BN=64 BK=32, 4 waves.
// LDS 24576 B unpadded -> 6 blocks/CU. Staging: 6x global_load_lds(16B)/tile;
// thread t's natural slot t*16 == row(t>>2), chunk(t&3) of the unpadded tile.
// Unpadded [r][32] frag reads distribute 64 lanes uniformly over the 8
// 16B-chunk slots (8 lanes/slot = LDS b128 throughput minimum) -> no pad.
struct ZD {
    const u16 *Ah, *Al, *Bh, *Bl;
    const float* bias;
    float* Cf; u16 *Ch, *Cl;
    int M, lda, ldb, ldc, K, act, omode;
    float scale;
};
template<int NZ> struct ZPack { ZD d[NZ]; };

__device__ __forceinline__ void gemm_zd(const ZD& dz, int m0, int n0,
    u16 (*Ash)[32], u16 (*Asl)[32], u16 (*Bsh)[32], u16 (*Bsl)[32])
{
    const int t  = threadIdx.x;
    const int lane = t & 63;
    const int wid  = t >> 6;
    const int wr = (wid >> 1) * 64;
    const int wc = (wid & 1) * 32;
    const int lr = lane & 15;
    const int lk = (lane >> 4) << 3;

    f32x4 acc[4][2];
    const f32x4 zero = {0.f, 0.f, 0.f, 0.f};
    #pragma unroll
    for (int i = 0; i < 4; ++i)
        #pragma unroll
        for (int j = 0; j < 2; ++j) acc[i][j] = zero;

    const int sr = t >> 2;            // staging row 0..63
    const int sc = (t & 3) << 3;      // staging k-offset (u16)
    char* AshB = (char*)&Ash[0][0];
    char* AslB = (char*)&Asl[0][0];
    char* BshB = (char*)&Bsh[0][0];
    char* BslB = (char*)&Bsl[0][0];
    const int wo = wid * 1024;        // wave-uniform LDS offset

    const long long arow0 = (long long)(m0 + sr) * dz.lda + sc;
    const long long arow1 = (long long)(m0 + 64 + sr) * dz.lda + sc;
    const long long brow  = (long long)(n0 + sr) * dz.ldb + sc;

    for (int k0 = 0; k0 < dz.K; k0 += 32) {
        __syncthreads();   // previous tile's frag reads done
        GLOAD16(dz.Ah + arow0 + k0, AshB + wo);
        GLOAD16(dz.Ah + arow1 + k0, AshB + 4096 + wo);
        GLOAD16(dz.Al + arow0 + k0, AslB + wo);
        GLOAD16(dz.Al + arow1 + k0, AslB + 4096 + wo);
        GLOAD16(dz.Bh + brow  + k0, BshB + wo);
        GLOAD16(dz.Bl + brow  + k0, BslB + wo);
        __syncthreads();   // barrier drains vmcnt(0): LDS tile complete

        short8 fah[4], fal[4], fbh[2], fbl[2];
        #pragma unroll
        for (int i = 0; i < 4; ++i) {
            fah[i] = *reinterpret_cast<const short8*>(&Ash[wr + i * 16 + lr][lk]);
            fal[i] = *reinterpret_cast<const short8*>(&Asl[wr + i * 16 + lr][lk]);
        }
        #pragma unroll
        for (int j = 0; j < 2; ++j) {
            fbh[j] = *reinterpret_cast<const short8*>(&Bsh[wc + j * 16 + lr][lk]);
            fbl[j] = *reinterpret_cast<const short8*>(&Bsl[wc + j * 16 + lr][lk]);
        }
        #pragma unroll
        for (int i = 0; i < 4; ++i)
            #pragma unroll
            for (int j = 0; j < 2; ++j) {
                acc[i][j] = __builtin_amdgcn_mfma_f32_16x16x32_bf16(fah[i], fbh[j], acc[i][j], 0, 0, 0);
                acc[i][j] = __builtin_amdgcn_mfma_f32_16x16x32_bf16(fah[i], fbl[j], acc[i][j], 0, 0, 0);
                acc[i][j] = __builtin_amdgcn_mfma_f32_16x16x32_bf16(fal[i], fbh[j], acc[i][j], 0, 0, 0);
            }
    }

    #pragma unroll
    for (int j = 0; j < 2; ++j) {
        const int col = n0 + wc + j * 16 + lr;
        const float bv = dz.bias ? dz.bias[col] : 0.f;
        #pragma unroll
        for (int i = 0; i < 4; ++i) {
            #pragma unroll
            for (int q = 0; q < 4; ++q) {
                const int row = m0 + wr + i * 16 + ((lane >> 4) << 2) + q;
                float v = (acc[i][j][q] + bv) * dz.scale;
                if (dz.act) v = tanhf(v);
                if (dz.omode == 0) {
                    dz.Cf[(long long)row * dz.ldc + col] = v;
                } else {
                    long long off = (dz.omode == 1)
                        ? (long long)row * dz.ldc + col
                        : (long long)col * dz.ldc + row;
                    u16 h = bf16_rn(v);
                    dz.Ch[off] = h;
                    dz.Cl[off] = bf16_rn(v - bf16_f(h));
                }
            }
        }
    }
}

template<int NZ>
__global__ __launch_bounds__(256)
void gemm_multi(ZPack<NZ> pk)
{
    __shared__ u16 Ash[128][32];
    __shared__ u16 Asl[128][32];
    __shared__ u16 Bsh[64][32];
    __shared__ u16 Bsl[64][32];
    const ZD dz = pk.d[blockIdx.z];
    const int m0 = blockIdx.x * 128;
    if (m0 >= dz.M) return;
    gemm_zd(dz, m0, blockIdx.y * 64, Ash, Asl, Bsh, Bsl);
}

// ======================= fused attention (device body) =====================
// 128 q-rows x 256 keys x 64 d; K in 2 halves; PV in 4 key-quarters; 72KB LDS.
// MODE 0: Q = qp1 slice, rows=q*16+bb; epilogue q-mean -> cb (ldc 512).
// MODE 1: Q = qp2; epilogue -> acat (ldc 1024, cols 0..511), NO uv term.
template<int MODE>
__device__ __forceinline__ void attn_body(char* smem, int bxblk, int h,
    const u16* __restrict__ Qph, const u16* __restrict__ Qpl,
    const u16* __restrict__ Kvh, const u16* __restrict__ Kvl,
    const u16* __restrict__ VTh, const u16* __restrict__ VTl,
    u16* __restrict__ Oh, u16* __restrict__ Ol)
{
    const int t = threadIdx.x;
    const int lane = t & 63, w = t >> 6;
    const int l15 = lane & 15, g = lane >> 4;
    const int wr = w * 32;
    const int b0 = bxblk * (MODE == 0 ? 16 : 128);

    u16* Qs = (u16*)smem;            // [2][128][72] = 36864 B
    char* KsB = smem + 36864;        // [2][128][72] u16 = 36864 B

    for (int c = t; c < 2048; c += 256) {
        int plane = c >> 10, rem = c & 1023;
        int row = rem >> 3, seg = rem & 7;
        const u16* src = plane ? Qpl : Qph;
        long long addr;
        if (MODE == 0) {
            int q = row >> 4, bb = row & 15;
            addr = ((long long)q * 2048 + b0 + bb) * 512 + h * 64 + seg * 8;
        } else {
            addr = (long long)(b0 + row) * 512 + h * 64 + seg * 8;
        }
        *(int4*)(&Qs[plane * 9216 + row * 72 + seg * 8]) = *(const int4*)(src + addr);
    }

    f32x4 sacc[2][16];
    const f32x4 zero = {0.f, 0.f, 0.f, 0.f};
    #pragma unroll
    for (int i = 0; i < 2; ++i)
        #pragma unroll
        for (int j = 0; j < 16; ++j) sacc[i][j] = zero;

    short8 qfh[2][2], qfl[2][2];

    for (int kh = 0; kh < 2; ++kh) {
        if (kh) __syncthreads();
        for (int c = t; c < 2048; c += 256) {
            int plane = c >> 10, rem = c & 1023;
            int key = rem >> 3, seg = rem & 7;
            const u16* src = plane ? Kvl : Kvh;
            *(int4*)(KsB + plane * 18432 + key * 144 + seg * 16) =
                *(const int4*)(src + (long long)(kh * 128 + key) * 1024 + h * 64 + seg * 8);
        }
        __syncthreads();
        if (kh == 0) {
            #pragma unroll
            for (int i = 0; i < 2; ++i)
                #pragma unroll
                for (int kf = 0; kf < 2; ++kf) {
                    int ro = (wr + 16 * i + l15) * 72 + kf * 32 + g * 8;
                    qfh[i][kf] = *(const short8*)(&Qs[ro]);
                    qfl[i][kf] = *(const short8*)(&Qs[9216 + ro]);
                }
        }
        #pragma unroll
        for (int j = 0; j < 8; ++j) {
            int jg = kh * 8 + j;
            #pragma unroll
            for (int kf = 0; kf < 2; ++kf) {
                const char* kb = KsB + (j * 16 + l15) * 144 + (kf * 32 + g * 8) * 2;
                short8 kbh = *(const short8*)(kb);
                short8 kbl = *(const short8*)(kb + 18432);
                #pragma unroll
                for (int i = 0; i < 2; ++i) {
                    sacc[i][jg] = __builtin_amdgcn_mfma_f32_16x16x32_bf16(qfh[i][kf], kbh, sacc[i][jg], 0, 0, 0);
                    sacc[i][jg] = __builtin_amdgcn_mfma_f32_16x16x32_bf16(qfh[i][kf], kbl, sacc[i][jg], 0, 0, 0);
                    sacc[i][jg] = __builtin_amdgcn_mfma_f32_16x16x32_bf16(qfl[i][kf], kbh, sacc[i][jg], 0, 0, 0);
                }
            }
        }
    }

    float inv[2][4];
    #pragma unroll
    for (int i = 0; i < 2; ++i)
        #pragma unroll
        for (int q = 0; q < 4; ++q) {
            float m = -1e30f;
            #pragma unroll
            for (int j = 0; j < 16; ++j) m = fmaxf(m, sacc[i][j][q]);
            #pragma unroll
            for (int off = 1; off <= 8; off <<= 1) m = fmaxf(m, __shfl_xor(m, off, 64));
            #pragma unroll
            for (int j = 0; j < 16; ++j) sacc[i][j][q] = __expf(sacc[i][j][q] - m);
            float s = 0.f;
            #pragma unroll
            for (int j = 0; j < 16; ++j) s += sacc[i][j][q];
            #pragma unroll
            for (int off = 1; off <= 8; off <<= 1) s += __shfl_xor(s, off, 64);
            inv[i][q] = 1.0f / s;
        }

    f32x4 ctx[2][4];
    #pragma unroll
    for (int i = 0; i < 2; ++i)
        #pragma unroll
        for (int jd = 0; jd < 4; ++jd) ctx[i][jd] = zero;

    for (int qt = 0; qt < 4; ++qt) {
        __syncthreads();
        #pragma unroll
        for (int i = 0; i < 2; ++i)
            #pragma unroll
            for (int jj = 0; jj < 4; ++jj) {
                int jg = qt * 4 + jj;
                #pragma unroll
                for (int q = 0; q < 4; ++q) {
                    int row = wr + 16 * i + 4 * g + q;
                    int key = jj * 16 + l15;
                    float pv = sacc[i][jg][q];
                    u16 ph = bf16_rn(pv);
                    u16 pl = bf16_rn(pv - bf16_f(ph));
                    int byt = row * 128 + ((key * 2) ^ ((row & 7) << 4));
                    *(u16*)(smem + byt) = ph;
                    *(u16*)(smem + 16384 + byt) = pl;
                }
            }
        for (int c = t; c < 1024; c += 256) {
            int plane = c >> 9, rem = c & 511;
            int d = rem >> 3, seg = rem & 7;
            const u16* src = plane ? VTl : VTh;
            int4 v = *(const int4*)(src + (long long)h * 16384 + d * 256 + qt * 64 + seg * 8);
            int byt = 36864 + plane * 8192 + d * 128 + ((seg * 16) ^ ((d & 7) << 4));
            *(int4*)(smem + byt) = v;
        }
        __syncthreads();

        short8 pah[2][2], pal[2][2];
        #pragma unroll
        for (int i = 0; i < 2; ++i)
            #pragma unroll
            for (int kf = 0; kf < 2; ++kf) {
                int row = wr + 16 * i + l15;
                int byt = row * 128 + ((kf * 64 + g * 16) ^ ((row & 7) << 4));
                pah[i][kf] = *(const short8*)(smem + byt);
                pal[i][kf] = *(const short8*)(smem + 16384 + byt);
            }
        #pragma unroll
        for (int jd = 0; jd < 4; ++jd) {
            #pragma unroll
            for (int kf = 0; kf < 2; ++kf) {
                int d = 16 * jd + l15;
                int byt = 36864 + d * 128 + ((kf * 64 + g * 16) ^ ((d & 7) << 4));
                short8 vbh = *(const short8*)(smem + byt);
                short8 vbl = *(const short8*)(smem + 8192 + byt);
                #pragma unroll
                for (int i = 0; i < 2; ++i) {
                    ctx[i][jd] = __builtin_amdgcn_mfma_f32_16x16x32_bf16(pah[i][kf], vbh, ctx[i][jd], 0, 0, 0);
                    ctx[i][jd] = __builtin_amdgcn_mfma_f32_16x16x32_bf16(pah[i][kf], vbl, ctx[i][jd], 0, 0, 0);
                    ctx[i][jd] = __builtin_amdgcn_mfma_f32_16x16x32_bf16(pal[i][kf], vbh, ctx[i][jd], 0, 0, 0);
                }
            }
        }
    }

    if (MODE == 0) {
        __syncthreads();
        float* R = (float*)smem;   // [8 q][16 b][64 d] = 32 KB
        #pragma unroll
        for (int i = 0; i < 2; ++i)
            #pragma unroll
            for (int jd = 0; jd < 4; ++jd)
                #pragma unroll
                for (int q = 0; q < 4; ++q) {
                    int qa = 2 * w + i;
                    int bb = 4 * g + q;
                    int d  = 16 * jd + l15;
                    R[qa * 1024 + bb * 64 + d] = ctx[i][jd][q] * inv[i][q];
                }
        __syncthreads();
        for (int o = t; o < 1024; o += 256) {
            int bb = o >> 6, d = o & 63;
            float s = 0.f;
            #pragma unroll
            for (int qa = 0; qa < 8; ++qa) s += R[qa * 1024 + bb * 64 + d];
            s *= 0.125f;
            long long addr = (long long)(b0 + bb) * 512 + h * 64 + d;
            u16 hh = bf16_rn(s);
            Oh[addr] = hh;
            Ol[addr] = bf16_rn(s - bf16_f(hh));
        }
    } else {
        #pragma unroll
        for (int i = 0; i < 2; ++i)
            #pragma unroll
            for (int jd = 0; jd < 4; ++jd)
                #pragma unroll
                for (int q = 0; q < 4; ++q) {
                    int b = b0 + wr + 16 * i + 4 * g + q;
                    int d = 16 * jd + l15;
                    long long addr = (long long)b * 1024 + h * 64 + d;   // acat
                    float v = ctx[i][jd][q] * inv[i][q];
                    u16 hh = bf16_rn(v);
                    Oh[addr] = hh;
                    Ol[addr] = bf16_rn(v - bf16_f(hh));
                }
    }
}

// ============== merged attn launch: attn1 (1024) + attn2 (128) =============
__global__ __launch_bounds__(256, 2)
void attn_both(const u16* __restrict__ Q1h, const u16* __restrict__ Q1l,
               const u16* __restrict__ Q2h, const u16* __restrict__ Q2l,
               const u16* __restrict__ Kvh, const u16* __restrict__ Kvl,
               const u16* __restrict__ VTh, const u16* __restrict__ VTl,
               u16* __restrict__ cbh, u16* __restrict__ cbl,
               u16* __restrict__ ach, u16* __restrict__ acl)
{
    extern __shared__ char smem[];
    const int id = blockIdx.x;
    if (id < 1024) {
        attn_body<0>(smem, id >> 3, id & 7, Q1h, Q1l, Kvh, Kvl, VTh, VTl,
                     cbh, cbl);
    } else {
        const int j = id - 1024;
        attn_body<1>(smem, j >> 3, j & 7, Q2h, Q2l, Kvh, Kvl, VTh, VTl,
                     ach, acl);
    }
}

// ======== write+final launch: final GEMM (256 blocks) + out1 write =========
__global__ __launch_bounds__(256)
void write_final(const u16* __restrict__ ach, const u16* __restrict__ acl,
                 const u16* __restrict__ bch, const u16* __restrict__ bcl,
                 const float* __restrict__ bias2, float* __restrict__ out,
                 const float* __restrict__ mem, const float* __restrict__ uf,
                 float* __restrict__ out1)
{
    __shared__ u16 Ash[128][32];
    __shared__ u16 Asl[128][32];
    __shared__ u16 Bsh[64][32];
    __shared__ u16 Bsl[64][32];
    const int id = blockIdx.x;
    if (id < 256) {
        ZD dz = { ach, acl, bch, bcl, bias2, out, nullptr, nullptr,
                  2048, 1024, 1024, 1024, 1024, 0, 0, 1.0f };
        gemm_zd(dz, (id & 15) * 128, (id >> 4) * 64, Ash, Asl, Bsh, Bsl);
    } else {
        const f32x4* m4 = reinterpret_cast<const f32x4*>(mem);
        const f32x4* u4 = reinterpret_cast<const f32x4*>(uf);
        f32x4* o4 = reinterpret_cast<f32x4*>(out1);
        long long i0 = (long long)(id - 256) * 16384 + threadIdx.x;
        #pragma unroll 4
        for (int j = 0; j < 64; ++j) {
            long long i = i0 + j * 256;
            int e4 = (int)(i & 127);
            int m  = (int)((i >> 7) & 255);
            long long b = i >> 15;
            f32x4 a = m4[m * 128 + e4];
            f32x4 c = u4[b * 128 + e4];
            f32x4 rr = a + c;
            __builtin_nontemporal_store(rr, &o4[i]);
        }
    }
}

extern "C" void kernel_launch(void* const* d_in, const int* in_sizes, int n_in,
                              void* d_out, int out_size, void* d_ws, size_t ws_size,
                              hipStream_t stream)
{
    (void)in_sizes; (void)n_in; (void)out_size; (void)ws_size;
    const float* x     = (const float*)d_in[0];
    const float* mem   = (const float*)d_in[1];
    const float* enc_w = (const float*)d_in[2];
    const float* enc_b = (const float*)d_in[3];
    const float* blk_w = (const float*)d_in[4];
    const float* blk_b = (const float*)d_in[5];
    const float* in_w  = (const float*)d_in[6];
    const float* in_b  = (const float*)d_in[7];
    const float* out_w = (const float*)d_in[8];
    const float* out_b = (const float*)d_in[9];
    const float* dec_w = (const float*)d_in[10];
    const float* dec_b = (const float*)d_in[11];
    float* out = (float*)d_out;

    // ---------------- workspace carve-up (256B-aligned) --------------------
    char* p = (char*)d_ws;
    auto alloc = [&](size_t bytes) { char* q = p; p += (bytes + 255) & ~(size_t)255; return q; };
    u16* xh   = (u16*)alloc(2097152 * 2); u16* xl   = (u16*)alloc(2097152 * 2);
    u16* memh = (u16*)alloc(131072 * 2);  u16* meml = (u16*)alloc(131072 * 2);
    u16* ewh  = (u16*)alloc(524288 * 2);  u16* ewl  = (u16*)alloc(524288 * 2);
    u16* iwh  = (u16*)alloc(786432 * 2);  u16* iwl  = (u16*)alloc(786432 * 2);
    u16* owh  = (u16*)alloc(262144 * 2);  u16* owl  = (u16*)alloc(262144 * 2);
    u16* owTh = (u16*)alloc(262144 * 2);  u16* owTl = (u16*)alloc(262144 * 2);
    u16* dwh  = (u16*)alloc(524288 * 2);  u16* dwl  = (u16*)alloc(524288 * 2);
    u16* ench = (u16*)alloc(1048576 * 2); u16* encl = (u16*)alloc(1048576 * 2);
    u16* kvh  = (u16*)alloc(262144 * 2);  u16* kvl  = (u16*)alloc(262144 * 2);
    u16* vpTh = (u16*)alloc(131072 * 2);  u16* vpTl = (u16*)alloc(131072 * 2);
    float* bias1  = (float*)alloc(4096 * 4);
    float* bias2  = (float*)alloc(1024 * 4);
    float* biasuv = (float*)alloc(512 * 4);
    u16* cbh  = (u16*)alloc(1048576 * 2); u16* cbl  = (u16*)alloc(1048576 * 2);
    float* uf = (float*)alloc(1048576 * 4);
    u16* qp2h = (u16*)alloc(1048576 * 2); u16* qp2l = (u16*)alloc(1048576 * 2);
    u16* Wuvh = (u16*)alloc(262144 * 2);  u16* Wuvl = (u16*)alloc(262144 * 2);
    u16* ach  = (u16*)alloc(2097152 * 2); u16* acl  = (u16*)alloc(2097152 * 2);   // [2048][1024]
    u16* bch  = (u16*)alloc(1048576 * 2); u16* bcl  = (u16*)alloc(1048576 * 2);   // [1024][1024]

    // ------ big scratch in the not-yet-written updated_memory region -------
    float* out1 = out + 2097152;
    u16* bwTh = (u16*)out1;               // [8][512][512]
    u16* bwTl = bwTh + 2097152;
    u16* W1h  = bwTl + 2097152;           // [8][512][512]
    u16* W1l  = W1h + 2097152;
    u16* qp1h = W1l + 2097152;            // [8][2048][512]
    u16* qp1l = qp1h + 8388608;

    dim3 blk(256);

    // 1. prep: split + transposes + folded biases
    prep_all<<<dim3(4374), blk, 0, stream>>>(x, mem, enc_w, in_w, out_w, dec_w,
        blk_w, in_b, blk_b, out_b, dec_b,
        xh, xl, memh, meml, ewh, ewl, iwh, iwl, owh, owl, dwh, dwl,
        bwTh, bwTl, owTh, owTl, bias1, bias2, biasuv);

    // 2. z=16 batch: enc, W1 x8, Wuv, W2-dup x4, kv(wk), vpT(wv transposed)
    {
        ZPack<16> pk;
        pk.d[0] = { xh, xl, ewh, ewl, enc_b, nullptr, ench, encl,
                    2048, 1024, 1024, 512, 1024, 1, 1, 1.0f };
        for (int z = 0; z < 8; ++z)
            pk.d[1 + z] = { iwh, iwl, bwTh + (long long)z * 262144, bwTl + (long long)z * 262144,
                            nullptr, nullptr, W1h + (long long)z * 262144, W1l + (long long)z * 262144,
                            512, 512, 512, 512, 512, 0, 1, 1.0f };
        pk.d[9]  = { iwh + 1024 * 512, iwl + 1024 * 512, owTh, owTl, nullptr,
                     nullptr, Wuvh, Wuvl, 512, 512, 512, 512, 512, 0, 1, 1.0f };
        // W2 = dec_w@out_w written TWICE into bcat cols [0,512) and [512,1024)
        for (int s = 0; s < 2; ++s)
            for (int c = 0; c < 2; ++c)
                pk.d[10 + s * 2 + c] = { dwh + (long long)s * 262144, dwl + (long long)s * 262144,
                                         owTh, owTl, nullptr, nullptr,
                                         bch + (long long)s * 524288 + c * 512,
                                         bcl + (long long)s * 524288 + c * 512,
                                         512, 512, 512, 1024, 512, 0, 1, 1.0f };
        pk.d[14] = { memh, meml, iwh + 512 * 512, iwl + 512 * 512, in_b + 512,
                     nullptr, kvh, kvl, 256, 512, 512, 1024, 512, 0, 1, 1.0f };
        pk.d[15] = { memh, meml, iwh + 1024 * 512, iwl + 1024 * 512, in_b + 1024,
                     nullptr, vpTh, vpTl, 256, 512, 512, 256, 512, 0, 2, 1.0f };
        gemm_multi<16><<<dim3(16, 8, 16), blk, 0, stream>>>(pk);
    }
    // 3. qp1 x8 + qp2   (z=9, 0.125 folded)
    {
        ZPack<9> pk;
        for (int z = 0; z < 8; ++z)
            pk.d[z] = { ench, encl, W1h + (long long)z * 262144, W1l + (long long)z * 262144,
                        bias1 + z * 512, nullptr,
                        qp1h + (long long)z * 1048576, qp1l + (long long)z * 1048576,
                        2048, 512, 512, 512, 512, 0, 1, 0.125f };
        pk.d[8] = { ench, encl, iwh, iwl, in_b, nullptr, qp2h, qp2l,
                    2048, 512, 512, 512, 512, 0, 1, 0.125f };
        gemm_multi<9><<<dim3(16, 8, 9), blk, 0, stream>>>(pk);
    }
    // 4. attn1 (-> cb) + attn2 (-> acat cols 0..511), one launch
    attn_both<<<dim3(1152), blk, 73728, stream>>>(qp1h, qp1l, qp2h, qp2l,
        kvh, kvl, vpTh, vpTl, cbh, cbl, ach, acl);
    // 5. u (f32) + uvb (-> acat cols 512..1023), batched
    {
        ZPack<2> pk;
        pk.d[0] = { cbh, cbl, owh, owl, out_b, uf, nullptr, nullptr,
                    2048, 512, 512, 512, 512, 0, 0, 1.0f };
        pk.d[1] = { cbh, cbl, Wuvh, Wuvl, biasuv, nullptr, ach + 512, acl + 512,
                    2048, 512, 512, 1024, 512, 0, 1, 1.0f };
        gemm_multi<2><<<dim3(16, 8, 2), blk, 0, stream>>>(pk);
    }
    // 6. final GEMM (K=1024 concat) rides the 1.07 GB out1 write
    //    (out-region scratch qp1/W1/bwT dead after step 4)
    write_final<<<dim3(4352), blk, 0, stream>>>(ach, acl, bch, bcl, bias2, out,
        mem, uf, out1);
}

// Round 10
// 472.950 us; speedup vs baseline: 1.4987x; 1.0312x over previous
//
#include <hip/hip_runtime.h>
#include <math.h>

// ---------------------------------------------------------------------------
// MemoryAugmentedNetwork — R9: R8 + stage rebalance for tail/fill:
//   stage2 = {enc, W1x8} (critical path only)
//   stage3 = {qp1x8, qp2, Wuv, W2x4, kv, vpT}  (single block-wave)
//   stage4 = attn1 only (1024 blocks = exactly 2 waves @ 2/CU)
//   stage5 = attn2 (128) + u/uvb GEMMs (256) merged
//   stage6 = final GEMM rides the 1.07 GB out1 write
// Shapes: B=2048, IN=1024, E=512, M=256, NB=H=8, D=64
// Algebra (exact): shared K/V; mean->out_w commute; MHA2 collapse;
// W1=wq@blk_w; Wuv=wv@out_w; final=[ctx2core|uvb]@[W2|W2]^T+bias2.
// Numerics: split-bf16 (a=ah+al), C=AhBh+AhBl+AlBh, f32 accum.
// ---------------------------------------------------------------------------

typedef __attribute__((ext_vector_type(8))) short short8;
typedef __attribute__((ext_vector_type(4))) float f32x4;
typedef unsigned short u16;

#define GLOAD16(gp, lp)                                                        \
    __builtin_amdgcn_global_load_lds(                                          \
        (const __attribute__((address_space(1))) void*)(gp),                   \
        (__attribute__((address_space(3))) void*)(lp), 16, 0, 0)

__device__ inline u16 bf16_rn(float x) {
    unsigned u = __float_as_uint(x);
    unsigned r = (u + 0x7FFFu + ((u >> 16) & 1u)) >> 16;
    return (u16)r;
}
__device__ inline float bf16_f(u16 h) { return __uint_as_float(((unsigned)h) << 16); }

// ======================= prep: split + transpose + bias ====================
__global__ __launch_bounds__(256)
void prep_all(const float* __restrict__ x, const float* __restrict__ mm,
              const float* __restrict__ ew, const float* __restrict__ iw,
              const float* __restrict__ ow, const float* __restrict__ dw,
              const float* __restrict__ blk_w,
              const float* __restrict__ in_b, const float* __restrict__ blk_b,
              const float* __restrict__ out_b, const float* __restrict__ dec_b,
              u16* __restrict__ xh, u16* __restrict__ xl,
              u16* __restrict__ mh, u16* __restrict__ ml,
              u16* __restrict__ ewh, u16* __restrict__ ewl,
              u16* __restrict__ iwh, u16* __restrict__ iwl,
              u16* __restrict__ owh, u16* __restrict__ owl,
              u16* __restrict__ dwh, u16* __restrict__ dwl,
              u16* __restrict__ bwTh, u16* __restrict__ bwTl,
              u16* __restrict__ owTh, u16* __restrict__ owTl,
              float* __restrict__ bias1, float* __restrict__ bias2,
              float* __restrict__ bias_uv)
{
    __shared__ float T[32][33];
    const int id = blockIdx.x;
    const int t = threadIdx.x;
    if (id < 2304) {
        const int z = id >> 8, within = id & 255;
        const float* s; u16 *dh, *dl;
        if (z < 8) { s = blk_w + (long long)z * 262144;
                     dh = bwTh + (long long)z * 262144; dl = bwTl + (long long)z * 262144; }
        else       { s = ow; dh = owTh; dl = owTl; }
        const int c0 = (within & 15) * 32, r0 = (within >> 4) * 32;
        const int tx = t & 31, ty = t >> 5;
        #pragma unroll
        for (int rr = 0; rr < 4; ++rr)
            T[ty + rr * 8][tx] = s[(long long)(r0 + ty + rr * 8) * 512 + c0 + tx];
        __syncthreads();
        #pragma unroll
        for (int rr = 0; rr < 4; ++rr) {
            float v = T[tx][ty + rr * 8];
            long long o = (long long)(c0 + ty + rr * 8) * 512 + r0 + tx;
            u16 hh = bf16_rn(v);
            dh[o] = hh; dl[o] = bf16_rn(v - bf16_f(hh));
        }
    } else if (id < 2326) {
        int idx = (id - 2304) * 256 + t;   // 5632
        if (idx < 4096) {
            int n = idx >> 9, f = idx & 511;
            const float* wr_ = iw + (long long)f * 512;
            const float* bb  = blk_b + n * 512;
            float s = in_b[f];
            for (int o = 0; o < 512; ++o) s += wr_[o] * bb[o];
            bias1[idx] = s;
        } else if (idx < 5120) {
            int i = idx - 4096;
            const float* dr = dw + (long long)i * 512;
            float s = dec_b[i];
            for (int f = 0; f < 512; ++f) s += dr[f] * out_b[f];
            bias2[i] = s;
        } else if (idx < 5632) {
            int f = idx - 5120;
            const float* wv = iw + (long long)(1024 + f) * 512;
            float s = 0.f;
            for (int e = 0; e < 512; ++e) s += wv[e] * out_b[e];
            bias_uv[f] = s;
        }
    } else {
        const long long total = 1081344;
        const long long stride = 2048LL * 256;
        for (long long i = (long long)(id - 2326) * 256 + t; i < total; i += stride) {
            const float* src; u16 *hi, *lo; long long j;
            if (i < 524288)      { src = x;  hi = xh;  lo = xl;  j = i; }
            else if (i < 557056) { src = mm; hi = mh;  lo = ml;  j = i - 524288; }
            else if (i < 688128) { src = ew; hi = ewh; lo = ewl; j = i - 557056; }
            else if (i < 884736) { src = iw; hi = iwh; lo = iwl; j = i - 688128; }
            else if (i < 950272) { src = ow; hi = owh; lo = owl; j = i - 884736; }
            else                 { src = dw; hi = dwh; lo = dwl; j = i - 950272; }
            float4 v = reinterpret_cast<const float4*>(src)[j];
            u16 h0 = bf16_rn(v.x), h1 = bf16_rn(v.y), h2 = bf16_rn(v.z), h3 = bf16_rn(v.w);
            ushort4 hv = {h0, h1, h2, h3};
            ushort4 lv = {bf16_rn(v.x - bf16_f(h0)), bf16_rn(v.y - bf16_f(h1)),
                          bf16_rn(v.z - bf16_f(h2)), bf16_rn(v.w - bf16_f(h3))};
            reinterpret_cast<ushort4*>(hi)[j] = hv;
            reinterpret_cast<ushort4*>(lo)[j] = lv;
        }
    }
}

// ========== generalized descriptor GEMM core (BK=32, global_load_lds) ======
struct ZD {
    const u16 *Ah, *Al, *Bh, *Bl;
    const float* bias;
    float* Cf; u16 *Ch, *Cl;
    int M, lda, ldb, ldc, K, act, omode;
    float scale;
};
template<int NZ> struct ZPack { ZD d[NZ]; };

__device__ __forceinline__ void gemm_zd(const ZD& dz, int m0, int n0,
    u16 (*Ash)[32], u16 (*Asl)[32], u16 (*Bsh)[32], u16 (*Bsl)[32])
{
    const int t  = threadIdx.x;
    const int lane = t & 63;
    const int wid  = t >> 6;
    const int wr = (wid >> 1) * 64;
    const int wc = (wid & 1) * 32;
    const int lr = lane & 15;
    const int lk = (lane >> 4) << 3;

    f32x4 acc[4][2];
    const f32x4 zero = {0.f, 0.f, 0.f, 0.f};
    #pragma unroll
    for (int i = 0; i < 4; ++i)
        #pragma unroll
        for (int j = 0; j < 2; ++j) acc[i][j] = zero;

    const int sr = t >> 2;
    const int sc = (t & 3) << 3;
    char* AshB = (char*)&Ash[0][0];
    char* AslB = (char*)&Asl[0][0];
    char* BshB = (char*)&Bsh[0][0];
    char* BslB = (char*)&Bsl[0][0];
    const int wo = wid * 1024;

    const long long arow0 = (long long)(m0 + sr) * dz.lda + sc;
    const long long arow1 = (long long)(m0 + 64 + sr) * dz.lda + sc;
    const long long brow  = (long long)(n0 + sr) * dz.ldb + sc;

    for (int k0 = 0; k0 < dz.K; k0 += 32) {
        __syncthreads();
        GLOAD16(dz.Ah + arow0 + k0, AshB + wo);
        GLOAD16(dz.Ah + arow1 + k0, AshB + 4096 + wo);
        GLOAD16(dz.Al + arow0 + k0, AslB + wo);
        GLOAD16(dz.Al + arow1 + k0, AslB + 4096 + wo);
        GLOAD16(dz.Bh + brow  + k0, BshB + wo);
        GLOAD16(dz.Bl + brow  + k0, BslB + wo);
        __syncthreads();

        short8 fah[4], fal[4], fbh[2], fbl[2];
        #pragma unroll
        for (int i = 0; i < 4; ++i) {
            fah[i] = *reinterpret_cast<const short8*>(&Ash[wr + i * 16 + lr][lk]);
            fal[i] = *reinterpret_cast<const short8*>(&Asl[wr + i * 16 + lr][lk]);
        }
        #pragma unroll
        for (int j = 0; j < 2; ++j) {
            fbh[j] = *reinterpret_cast<const short8*>(&Bsh[wc + j * 16 + lr][lk]);
            fbl[j] = *reinterpret_cast<const short8*>(&Bsl[wc + j * 16 + lr][lk]);
        }
        #pragma unroll
        for (int i = 0; i < 4; ++i)
            #pragma unroll
            for (int j = 0; j < 2; ++j) {
                acc[i][j] = __builtin_amdgcn_mfma_f32_16x16x32_bf16(fah[i], fbh[j], acc[i][j], 0, 0, 0);
                acc[i][j] = __builtin_amdgcn_mfma_f32_16x16x32_bf16(fah[i], fbl[j], acc[i][j], 0, 0, 0);
                acc[i][j] = __builtin_amdgcn_mfma_f32_16x16x32_bf16(fal[i], fbh[j], acc[i][j], 0, 0, 0);
            }
    }

    #pragma unroll
    for (int j = 0; j < 2; ++j) {
        const int col = n0 + wc + j * 16 + lr;
        const float bv = dz.bias ? dz.bias[col] : 0.f;
        #pragma unroll
        for (int i = 0; i < 4; ++i) {
            #pragma unroll
            for (int q = 0; q < 4; ++q) {
                const int row = m0 + wr + i * 16 + ((lane >> 4) << 2) + q;
                float v = (acc[i][j][q] + bv) * dz.scale;
                if (dz.act) v = tanhf(v);
                if (dz.omode == 0) {
                    dz.Cf[(long long)row * dz.ldc + col] = v;
                } else {
                    long long off = (dz.omode == 1)
                        ? (long long)row * dz.ldc + col
                        : (long long)col * dz.ldc + row;
                    u16 h = bf16_rn(v);
                    dz.Ch[off] = h;
                    dz.Cl[off] = bf16_rn(v - bf16_f(h));
                }
            }
        }
    }
}

template<int NZ>
__global__ __launch_bounds__(256)
void gemm_multi(ZPack<NZ> pk)
{
    __shared__ u16 Ash[128][32];
    __shared__ u16 Asl[128][32];
    __shared__ u16 Bsh[64][32];
    __shared__ u16 Bsl[64][32];
    const ZD dz = pk.d[blockIdx.z];
    const int m0 = blockIdx.x * 128;
    if (m0 >= dz.M) return;
    gemm_zd(dz, m0, blockIdx.y * 64, Ash, Asl, Bsh, Bsl);
}

// ======================= fused attention (device body) =====================
// MODE 0: Q = qp1 slice, rows=q*16+bb; epilogue q-mean -> cb (ldc 512).
// MODE 1: Q = qp2; epilogue -> acat (ldc 1024, cols 0..511).
template<int MODE>
__device__ __forceinline__ void attn_body(char* smem, int bxblk, int h,
    const u16* __restrict__ Qph, const u16* __restrict__ Qpl,
    const u16* __restrict__ Kvh, const u16* __restrict__ Kvl,
    const u16* __restrict__ VTh, const u16* __restrict__ VTl,
    u16* __restrict__ Oh, u16* __restrict__ Ol)
{
    const int t = threadIdx.x;
    const int lane = t & 63, w = t >> 6;
    const int l15 = lane & 15, g = lane >> 4;
    const int wr = w * 32;
    const int b0 = bxblk * (MODE == 0 ? 16 : 128);

    u16* Qs = (u16*)smem;            // [2][128][72] = 36864 B
    char* KsB = smem + 36864;        // [2][128][72] u16 = 36864 B

    for (int c = t; c < 2048; c += 256) {
        int plane = c >> 10, rem = c & 1023;
        int row = rem >> 3, seg = rem & 7;
        const u16* src = plane ? Qpl : Qph;
        long long addr;
        if (MODE == 0) {
            int q = row >> 4, bb = row & 15;
            addr = ((long long)q * 2048 + b0 + bb) * 512 + h * 64 + seg * 8;
        } else {
            addr = (long long)(b0 + row) * 512 + h * 64 + seg * 8;
        }
        *(int4*)(&Qs[plane * 9216 + row * 72 + seg * 8]) = *(const int4*)(src + addr);
    }

    f32x4 sacc[2][16];
    const f32x4 zero = {0.f, 0.f, 0.f, 0.f};
    #pragma unroll
    for (int i = 0; i < 2; ++i)
        #pragma unroll
        for (int j = 0; j < 16; ++j) sacc[i][j] = zero;

    short8 qfh[2][2], qfl[2][2];

    for (int kh = 0; kh < 2; ++kh) {
        if (kh) __syncthreads();
        for (int c = t; c < 2048; c += 256) {
            int plane = c >> 10, rem = c & 1023;
            int key = rem >> 3, seg = rem & 7;
            const u16* src = plane ? Kvl : Kvh;
            *(int4*)(KsB + plane * 18432 + key * 144 + seg * 16) =
                *(const int4*)(src + (long long)(kh * 128 + key) * 1024 + h * 64 + seg * 8);
        }
        __syncthreads();
        if (kh == 0) {
            #pragma unroll
            for (int i = 0; i < 2; ++i)
                #pragma unroll
                for (int kf = 0; kf < 2; ++kf) {
                    int ro = (wr + 16 * i + l15) * 72 + kf * 32 + g * 8;
                    qfh[i][kf] = *(const short8*)(&Qs[ro]);
                    qfl[i][kf] = *(const short8*)(&Qs[9216 + ro]);
                }
        }
        #pragma unroll
        for (int j = 0; j < 8; ++j) {
            int jg = kh * 8 + j;
            #pragma unroll
            for (int kf = 0; kf < 2; ++kf) {
                const char* kb = KsB + (j * 16 + l15) * 144 + (kf * 32 + g * 8) * 2;
                short8 kbh = *(const short8*)(kb);
                short8 kbl = *(const short8*)(kb + 18432);
                #pragma unroll
                for (int i = 0; i < 2; ++i) {
                    sacc[i][jg] = __builtin_amdgcn_mfma_f32_16x16x32_bf16(qfh[i][kf], kbh, sacc[i][jg], 0, 0, 0);
                    sacc[i][jg] = __builtin_amdgcn_mfma_f32_16x16x32_bf16(qfh[i][kf], kbl, sacc[i][jg], 0, 0, 0);
                    sacc[i][jg] = __builtin_amdgcn_mfma_f32_16x16x32_bf16(qfl[i][kf], kbh, sacc[i][jg], 0, 0, 0);
                }
            }
        }
    }

    float inv[2][4];
    #pragma unroll
    for (int i = 0; i < 2; ++i)
        #pragma unroll
        for (int q = 0; q < 4; ++q) {
            float m = -1e30f;
            #pragma unroll
            for (int j = 0; j < 16; ++j) m = fmaxf(m, sacc[i][j][q]);
            #pragma unroll
            for (int off = 1; off <= 8; off <<= 1) m = fmaxf(m, __shfl_xor(m, off, 64));
            #pragma unroll
            for (int j = 0; j < 16; ++j) sacc[i][j][q] = __expf(sacc[i][j][q] - m);
            float s = 0.f;
            #pragma unroll
            for (int j = 0; j < 16; ++j) s += sacc[i][j][q];
            #pragma unroll
            for (int off = 1; off <= 8; off <<= 1) s += __shfl_xor(s, off, 64);
            inv[i][q] = 1.0f / s;
        }

    f32x4 ctx[2][4];
    #pragma unroll
    for (int i = 0; i < 2; ++i)
        #pragma unroll
        for (int jd = 0; jd < 4; ++jd) ctx[i][jd] = zero;

    for (int qt = 0; qt < 4; ++qt) {
        __syncthreads();
        #pragma unroll
        for (int i = 0; i < 2; ++i)
            #pragma unroll
            for (int jj = 0; jj < 4; ++jj) {
                int jg = qt * 4 + jj;
                #pragma unroll
                for (int q = 0; q < 4; ++q) {
                    int row = wr + 16 * i + 4 * g + q;
                    int key = jj * 16 + l15;
                    float pv = sacc[i][jg][q];
                    u16 ph = bf16_rn(pv);
                    u16 pl = bf16_rn(pv - bf16_f(ph));
                    int byt = row * 128 + ((key * 2) ^ ((row & 7) << 4));
                    *(u16*)(smem + byt) = ph;
                    *(u16*)(smem + 16384 + byt) = pl;
                }
            }
        for (int c = t; c < 1024; c += 256) {
            int plane = c >> 9, rem = c & 511;
            int d = rem >> 3, seg = rem & 7;
            const u16* src = plane ? VTl : VTh;
            int4 v = *(const int4*)(src + (long long)h * 16384 + d * 256 + qt * 64 + seg * 8);
            int byt = 36864 + plane * 8192 + d * 128 + ((seg * 16) ^ ((d & 7) << 4));
            *(int4*)(smem + byt) = v;
        }
        __syncthreads();

        short8 pah[2][2], pal[2][2];
        #pragma unroll
        for (int i = 0; i < 2; ++i)
            #pragma unroll
            for (int kf = 0; kf < 2; ++kf) {
                int row = wr + 16 * i + l15;
                int byt = row * 128 + ((kf * 64 + g * 16) ^ ((row & 7) << 4));
                pah[i][kf] = *(const short8*)(smem + byt);
                pal[i][kf] = *(const short8*)(smem + 16384 + byt);
            }
        #pragma unroll
        for (int jd = 0; jd < 4; ++jd) {
            #pragma unroll
            for (int kf = 0; kf < 2; ++kf) {
                int d = 16 * jd + l15;
                int byt = 36864 + d * 128 + ((kf * 64 + g * 16) ^ ((d & 7) << 4));
                short8 vbh = *(const short8*)(smem + byt);
                short8 vbl = *(const short8*)(smem + 8192 + byt);
                #pragma unroll
                for (int i = 0; i < 2; ++i) {
                    ctx[i][jd] = __builtin_amdgcn_mfma_f32_16x16x32_bf16(pah[i][kf], vbh, ctx[i][jd], 0, 0, 0);
                    ctx[i][jd] = __builtin_amdgcn_mfma_f32_16x16x32_bf16(pah[i][kf], vbl, ctx[i][jd], 0, 0, 0);
                    ctx[i][jd] = __builtin_amdgcn_mfma_f32_16x16x32_bf16(pal[i][kf], vbh, ctx[i][jd], 0, 0, 0);
                }
            }
        }
    }

    if (MODE == 0) {
        __syncthreads();
        float* R = (float*)smem;   // [8 q][16 b][64 d] = 32 KB
        #pragma unroll
        for (int i = 0; i < 2; ++i)
            #pragma unroll
            for (int jd = 0; jd < 4; ++jd)
                #pragma unroll
                for (int q = 0; q < 4; ++q) {
                    int qa = 2 * w + i;
                    int bb = 4 * g + q;
                    int d  = 16 * jd + l15;
                    R[qa * 1024 + bb * 64 + d] = ctx[i][jd][q] * inv[i][q];
                }
        __syncthreads();
        for (int o = t; o < 1024; o += 256) {
            int bb = o >> 6, d = o & 63;
            float s = 0.f;
            #pragma unroll
            for (int qa = 0; qa < 8; ++qa) s += R[qa * 1024 + bb * 64 + d];
            s *= 0.125f;
            long long addr = (long long)(b0 + bb) * 512 + h * 64 + d;
            u16 hh = bf16_rn(s);
            Oh[addr] = hh;
            Ol[addr] = bf16_rn(s - bf16_f(hh));
        }
    } else {
        #pragma unroll
        for (int i = 0; i < 2; ++i)
            #pragma unroll
            for (int jd = 0; jd < 4; ++jd)
                #pragma unroll
                for (int q = 0; q < 4; ++q) {
                    int b = b0 + wr + 16 * i + 4 * g + q;
                    int d = 16 * jd + l15;
                    long long addr = (long long)b * 1024 + h * 64 + d;   // acat
                    float v = ctx[i][jd][q] * inv[i][q];
                    u16 hh = bf16_rn(v);
                    Oh[addr] = hh;
                    Ol[addr] = bf16_rn(v - bf16_f(hh));
                }
    }
}

// ===================== stage 4: attn1 only (1024 blocks) ===================
__global__ __launch_bounds__(256, 2)
void attn1_k(const u16* __restrict__ Q1h, const u16* __restrict__ Q1l,
             const u16* __restrict__ Kvh, const u16* __restrict__ Kvl,
             const u16* __restrict__ VTh, const u16* __restrict__ VTl,
             u16* __restrict__ cbh, u16* __restrict__ cbl)
{
    extern __shared__ char smem[];
    attn_body<0>(smem, blockIdx.x >> 3, blockIdx.x & 7, Q1h, Q1l,
                 Kvh, Kvl, VTh, VTl, cbh, cbl);
}

// ======== stage 5: attn2 (128 blocks) + u/uvb GEMMs (256 blocks) ===========
__global__ __launch_bounds__(256, 2)
void attn2_u(const u16* __restrict__ Q2h, const u16* __restrict__ Q2l,
             const u16* __restrict__ Kvh, const u16* __restrict__ Kvl,
             const u16* __restrict__ VTh, const u16* __restrict__ VTl,
             u16* __restrict__ ach, u16* __restrict__ acl,
             ZPack<2> pk)
{
    extern __shared__ char smem[];
    const int id = blockIdx.x;
    if (id < 128) {
        attn_body<1>(smem, id >> 3, id & 7, Q2h, Q2l, Kvh, Kvl, VTh, VTl,
                     ach, acl);
    } else {
        const int gid = id - 128;            // 0..255
        const ZD dz = pk.d[gid >> 7];
        const int w = gid & 127;
        gemm_zd(dz, (w & 15) * 128, (w >> 4) * 64,
                (u16(*)[32])(smem),
                (u16(*)[32])(smem + 8192),
                (u16(*)[32])(smem + 16384),
                (u16(*)[32])(smem + 20480));
    }
}

// ======== stage 6: final GEMM (256 blocks) + out1 write ====================
__global__ __launch_bounds__(256)
void write_final(const u16* __restrict__ ach, const u16* __restrict__ acl,
                 const u16* __restrict__ bch, const u16* __restrict__ bcl,
                 const float* __restrict__ bias2, float* __restrict__ out,
                 const float* __restrict__ mem, const float* __restrict__ uf,
                 float* __restrict__ out1)
{
    __shared__ u16 Ash[128][32];
    __shared__ u16 Asl[128][32];
    __shared__ u16 Bsh[64][32];
    __shared__ u16 Bsl[64][32];
    const int id = blockIdx.x;
    if (id < 256) {
        ZD dz = { ach, acl, bch, bcl, bias2, out, nullptr, nullptr,
                  2048, 1024, 1024, 1024, 1024, 0, 0, 1.0f };
        gemm_zd(dz, (id & 15) * 128, (id >> 4) * 64, Ash, Asl, Bsh, Bsl);
    } else {
        const f32x4* m4 = reinterpret_cast<const f32x4*>(mem);
        const f32x4* u4 = reinterpret_cast<const f32x4*>(uf);
        f32x4* o4 = reinterpret_cast<f32x4*>(out1);
        long long i0 = (long long)(id - 256) * 16384 + threadIdx.x;
        #pragma unroll 4
        for (int j = 0; j < 64; ++j) {
            long long i = i0 + j * 256;
            int e4 = (int)(i & 127);
            int m  = (int)((i >> 7) & 255);
            long long b = i >> 15;
            f32x4 a = m4[m * 128 + e4];
            f32x4 c = u4[b * 128 + e4];
            f32x4 rr = a + c;
            __builtin_nontemporal_store(rr, &o4[i]);
        }
    }
}

extern "C" void kernel_launch(void* const* d_in, const int* in_sizes, int n_in,
                              void* d_out, int out_size, void* d_ws, size_t ws_size,
                              hipStream_t stream)
{
    (void)in_sizes; (void)n_in; (void)out_size; (void)ws_size;
    const float* x     = (const float*)d_in[0];
    const float* mem   = (const float*)d_in[1];
    const float* enc_w = (const float*)d_in[2];
    const float* enc_b = (const float*)d_in[3];
    const float* blk_w = (const float*)d_in[4];
    const float* blk_b = (const float*)d_in[5];
    const float* in_w  = (const float*)d_in[6];
    const float* in_b  = (const float*)d_in[7];
    const float* out_w = (const float*)d_in[8];
    const float* out_b = (const float*)d_in[9];
    const float* dec_w = (const float*)d_in[10];
    const float* dec_b = (const float*)d_in[11];
    float* out = (float*)d_out;

    // ---------------- workspace carve-up (256B-aligned) --------------------
    char* p = (char*)d_ws;
    auto alloc = [&](size_t bytes) { char* q = p; p += (bytes + 255) & ~(size_t)255; return q; };
    u16* xh   = (u16*)alloc(2097152 * 2); u16* xl   = (u16*)alloc(2097152 * 2);
    u16* memh = (u16*)alloc(131072 * 2);  u16* meml = (u16*)alloc(131072 * 2);
    u16* ewh  = (u16*)alloc(524288 * 2);  u16* ewl  = (u16*)alloc(524288 * 2);
    u16* iwh  = (u16*)alloc(786432 * 2);  u16* iwl  = (u16*)alloc(786432 * 2);
    u16* owh  = (u16*)alloc(262144 * 2);  u16* owl  = (u16*)alloc(262144 * 2);
    u16* owTh = (u16*)alloc(262144 * 2);  u16* owTl = (u16*)alloc(262144 * 2);
    u16* dwh  = (u16*)alloc(524288 * 2);  u16* dwl  = (u16*)alloc(524288 * 2);
    u16* ench = (u16*)alloc(1048576 * 2); u16* encl = (u16*)alloc(1048576 * 2);
    u16* kvh  = (u16*)alloc(262144 * 2);  u16* kvl  = (u16*)alloc(262144 * 2);
    u16* vpTh = (u16*)alloc(131072 * 2);  u16* vpTl = (u16*)alloc(131072 * 2);
    float* bias1  = (float*)alloc(4096 * 4);
    float* bias2  = (float*)alloc(1024 * 4);
    float* biasuv = (float*)alloc(512 * 4);
    u16* cbh  = (u16*)alloc(1048576 * 2); u16* cbl  = (u16*)alloc(1048576 * 2);
    float* uf = (float*)alloc(1048576 * 4);
    u16* qp2h = (u16*)alloc(1048576 * 2); u16* qp2l = (u16*)alloc(1048576 * 2);
    u16* Wuvh = (u16*)alloc(262144 * 2);  u16* Wuvl = (u16*)alloc(262144 * 2);
    u16* ach  = (u16*)alloc(2097152 * 2); u16* acl  = (u16*)alloc(2097152 * 2);   // [2048][1024]
    u16* bch  = (u16*)alloc(1048576 * 2); u16* bcl  = (u16*)alloc(1048576 * 2);   // [1024][1024]

    // ------ big scratch in the not-yet-written updated_memory region -------
    float* out1 = out + 2097152;
    u16* bwTh = (u16*)out1;               // [8][512][512]
    u16* bwTl = bwTh + 2097152;
    u16* W1h  = bwTl + 2097152;           // [8][512][512]
    u16* W1l  = W1h + 2097152;
    u16* qp1h = W1l + 2097152;            // [8][2048][512]
    u16* qp1l = qp1h + 8388608;

    dim3 blk(256);

    // 1. prep: split + transposes + folded biases
    prep_all<<<dim3(4374), blk, 0, stream>>>(x, mem, enc_w, in_w, out_w, dec_w,
        blk_w, in_b, blk_b, out_b, dec_b,
        xh, xl, memh, meml, ewh, ewl, iwh, iwl, owh, owl, dwh, dwl,
        bwTh, bwTl, owTh, owTl, bias1, bias2, biasuv);

    // 2. critical path only: enc + W1 x8   (z=9)
    {
        ZPack<9> pk;
        pk.d[0] = { xh, xl, ewh, ewl, enc_b, nullptr, ench, encl,
                    2048, 1024, 1024, 512, 1024, 1, 1, 1.0f };
        for (int z = 0; z < 8; ++z)
            pk.d[1 + z] = { iwh, iwl, bwTh + (long long)z * 262144, bwTl + (long long)z * 262144,
                            nullptr, nullptr, W1h + (long long)z * 262144, W1l + (long long)z * 262144,
                            512, 512, 512, 512, 512, 0, 1, 1.0f };
        gemm_multi<9><<<dim3(16, 8, 9), blk, 0, stream>>>(pk);
    }
    // 3. qp1 x8, qp2, Wuv, W2 x4, kv, vpT   (z=16, single block-wave)
    {
        ZPack<16> pk;
        for (int z = 0; z < 8; ++z)
            pk.d[z] = { ench, encl, W1h + (long long)z * 262144, W1l + (long long)z * 262144,
                        bias1 + z * 512, nullptr,
                        qp1h + (long long)z * 1048576, qp1l + (long long)z * 1048576,
                        2048, 512, 512, 512, 512, 0, 1, 0.125f };
        pk.d[8] = { ench, encl, iwh, iwl, in_b, nullptr, qp2h, qp2l,
                    2048, 512, 512, 512, 512, 0, 1, 0.125f };
        pk.d[9]  = { iwh + 1024 * 512, iwl + 1024 * 512, owTh, owTl, nullptr,
                     nullptr, Wuvh, Wuvl, 512, 512, 512, 512, 512, 0, 1, 1.0f };
        for (int s = 0; s < 2; ++s)
            for (int c = 0; c < 2; ++c)
                pk.d[10 + s * 2 + c] = { dwh + (long long)s * 262144, dwl + (long long)s * 262144,
                                         owTh, owTl, nullptr, nullptr,
                                         bch + (long long)s * 524288 + c * 512,
                                         bcl + (long long)s * 524288 + c * 512,
                                         512, 512, 512, 1024, 512, 0, 1, 1.0f };
        pk.d[14] = { memh, meml, iwh + 512 * 512, iwl + 512 * 512, in_b + 512,
                     nullptr, kvh, kvl, 256, 512, 512, 1024, 512, 0, 1, 1.0f };
        pk.d[15] = { memh, meml, iwh + 1024 * 512, iwl + 1024 * 512, in_b + 1024,
                     nullptr, vpTh, vpTl, 256, 512, 512, 256, 512, 0, 2, 1.0f };
        gemm_multi<16><<<dim3(16, 8, 16), blk, 0, stream>>>(pk);
    }
    // 4. attn1 only: 1024 blocks = exactly 2 waves @ 2 blocks/CU
    attn1_k<<<dim3(1024), blk, 73728, stream>>>(qp1h, qp1l, kvh, kvl,
        vpTh, vpTl, cbh, cbl);
    // 5. attn2 (128) + u/uvb GEMMs (256), one launch
    {
        ZPack<2> pk;
        pk.d[0] = { cbh, cbl, owh, owl, out_b, uf, nullptr, nullptr,
                    2048, 512, 512, 512, 512, 0, 0, 1.0f };
        pk.d[1] = { cbh, cbl, Wuvh, Wuvl, biasuv, nullptr, ach + 512, acl + 512,
                    2048, 512, 512, 1024, 512, 0, 1, 1.0f };
        attn2_u<<<dim3(384), blk, 73728, stream>>>(qp2h, qp2l, kvh, kvl,
            vpTh, vpTl, ach, acl, pk);
    }
    // 6. final GEMM (K=1024 concat) rides the 1.07 GB out1 write
    //    (out-region scratch qp1/W1/bwT dead after step 4)
    write_final<<<dim3(4352), blk, 0, stream>>>(ach, acl, bch, bcl, bias2, out,
        mem, uf, out1);
}